// Round 10
// baseline (525.666 us; speedup 1.0000x reference)
//
#include <hip/hip_runtime.h>
#include <hip/hip_bf16.h>
#include <type_traits>

#define DIN   7686
#define NNODE 7946
#define HOUT  260
#define KP    8192   // padded k (64 tiles of 128)
#define PLDS  2056

typedef __attribute__((ext_vector_type(8))) short bf16x8;
typedef __attribute__((ext_vector_type(4))) float f32x4;

__device__ __forceinline__ unsigned int f2b(float f) {
  union { float f; unsigned int u; } v; v.f = f;
  return (v.u + 0x7FFFu + ((v.u >> 16) & 1u)) >> 16;  // RNE float->bf16
}
__device__ __forceinline__ unsigned int pack2(float lo, float hi) {
  unsigned int r;
  asm("v_cvt_pk_bf16_f32 %0, %1, %2" : "=v"(r) : "v"(lo), "v"(hi));
  return r;
}
__device__ __forceinline__ float b2f(unsigned short h) {
  union { unsigned int u; float f; } v; v.u = ((unsigned int)h) << 16; return v.f;
}
__device__ __forceinline__ float readlane_f(float v, int lane) {
  return __uint_as_float(__builtin_amdgcn_readlane(__float_as_uint(v), lane));
}
__device__ __forceinline__ void gload16(const void* g, void* l) {
  __builtin_amdgcn_global_load_lds(
      (const __attribute__((address_space(1))) unsigned int*)g,
      (__attribute__((address_space(3))) unsigned int*)l, 16, 0, 0);
}

// ---------------------------------------------------------------------------
// PROBE A: m13-exact stream of Wq. float4/lane grid-stride, no LDS, no deps.
// ---------------------------------------------------------------------------
__global__ __launch_bounds__(256)
void probe_f4(const float* __restrict__ W, float* __restrict__ out)
{
  const size_t N4 = (size_t)DIN * DIN / 4;
  const size_t stride = (size_t)gridDim.x * 256;
  size_t idx = (size_t)blockIdx.x * 256 + threadIdx.x;
  float s = 0.f;
  for (; idx < N4; idx += stride) {
    float4 v = *(const float4*)(W + idx * 4);
    s += v.x + v.y + v.z + v.w;
  }
#pragma unroll
  for (int o = 32; o >= 1; o >>= 1) s += __shfl_xor(s, o, 64);
  if ((threadIdx.x & 63) == 0)
    out[blockIdx.x * 4 + (threadIdx.x >> 6)] = s;
}

// ---------------------------------------------------------------------------
// PROBE B: R9-phase1 verbatim on Wk. float2 pairs + pack + LDS write, 1 WG/CU.
// ---------------------------------------------------------------------------
__global__ __launch_bounds__(512, 1)
void probe_f2s(const float* __restrict__ W, float* __restrict__ out)
{
  const int z = blockIdx.z;
  const int n0 = blockIdx.x * 32;
  const int tid = threadIdx.x, l = tid & 63, wv = tid >> 6;
  __shared__ __align__(16) unsigned short Bp[32 * PLDS];
  const long long DD = (long long)DIN * DIN;
  const int kq0 = z * 2048;
#pragma unroll
  for (int r = 0; r < 4; ++r) {
    const int lrow = wv * 4 + r;
    int grow = n0 + lrow; if (grow > DIN - 1) grow = DIN - 1;
    const long long gbase = (long long)grow * DIN + kq0;
    unsigned short* dst = &Bp[lrow * PLDS];
#pragma unroll
    for (int c = 0; c < 8; ++c) {
      const int k = c * 256 + l * 4;
      long long g0 = gbase + k, g1 = gbase + k + 2;
      if (g0 + 2 > DD) g0 = DD - 2;
      if (g1 + 2 > DD) g1 = DD - 2;
      float2 v0 = *(const float2*)(W + g0);
      float2 v1 = *(const float2*)(W + g1);
      uint2 o; o.x = pack2(v0.x, v0.y); o.y = pack2(v1.x, v1.y);
      *(uint2*)(dst + k) = o;
    }
  }
  __syncthreads();
  float s = 0.f;
#pragma unroll
  for (int h = 0; h < 8; ++h) s += b2f(Bp[tid * 8 + h]);
#pragma unroll
  for (int o = 32; o >= 1; o >>= 1) s += __shfl_xor(s, o, 64);
  if (l == 0) out[(z * 241 + blockIdx.x) * 8 + wv] = s;
}

// ---------------------------------------------------------------------------
// prep: fp32 X -> bf16, tiled+swizzled (R6 verified)
// ---------------------------------------------------------------------------
__global__ void prep_x(const float* __restrict__ X, unsigned short* __restrict__ XbT)
{
  const int m = blockIdx.x, t = threadIdx.x;
  const float* row = X + (size_t)m * DIN;
#pragma unroll
  for (int c2 = 0; c2 < 4; ++c2) {
    const int k8 = (c2 * 256 + t) * 8;
    float f[8];
    if (k8 + 8 <= DIN) {
#pragma unroll
      for (int h = 0; h < 4; ++h) {
        float2 v = *(const float2*)(row + k8 + h * 2);
        f[h * 2] = v.x; f[h * 2 + 1] = v.y;
      }
    } else {
#pragma unroll
      for (int h = 0; h < 8; ++h) f[h] = (k8 + h < DIN) ? row[k8 + h] : 0.f;
    }
    uint4 o;
    o.x = pack2(f[0], f[1]); o.y = pack2(f[2], f[3]);
    o.z = pack2(f[4], f[5]); o.w = pack2(f[6], f[7]);
    const int kc = k8 >> 7;
    char* dst = (char*)XbT + (size_t)kc * 65536 + m * 256 +
                (((k8 & 127) * 2) ^ ((m & 7) << 4));
    *(uint4*)dst = o;
  }
}

// ---------------------------------------------------------------------------
// gemm_qk2 (R6 verified): BM=256 BN=64 BK=128, 64 steps.
// ---------------------------------------------------------------------------
__global__ __launch_bounds__(512)
void gemm_qk2(const unsigned short* __restrict__ XbT,
              const float* __restrict__ Wq, const float* __restrict__ Wk,
              const float* __restrict__ bq, const float* __restrict__ bk,
              unsigned short* __restrict__ Qbf, unsigned short* __restrict__ Kbf)
{
  const int mat = blockIdx.y;
  const float* W = mat ? Wk : Wq;
  const float* bias = mat ? bk : bq;
  unsigned short* Out = mat ? Kbf : Qbf;
  const int nt = blockIdx.x, n0 = nt * 64;
  const int tid = threadIdx.x, l = tid & 63, wv = tid >> 6;
  const int wr = wv >> 1, wc = wv & 1;
  const int lm = l & 15;

  __shared__ __align__(16) unsigned short As[2][32768];
  __shared__ __align__(16) unsigned short Bs[8192];

  long long wrb[8];
#pragma unroll
  for (int r = 0; r < 8; ++r) {
    int rg = n0 + wv * 8 + r;
    if (rg > DIN - 1) rg = DIN - 1;
    wrb[r] = (long long)rg * DIN;
  }

  float2 breg[8];
  auto RLOADB = [&](int s) {
    const int ss = (s < 64) ? s : 63;
    const int kk = ss * 128 + l * 2;
    const int kcl = (kk < DIN) ? kk : 0;
    const bool ok = kk < DIN;
#pragma unroll
    for (int r = 0; r < 8; ++r) {
      float2 v = *(const float2*)(W + wrb[r] + kcl);
      if (!ok) { v.x = 0.f; v.y = 0.f; }
      breg[r] = v;
    }
  };
  auto SWRITE = [&]() {
#pragma unroll
    for (int r = 0; r < 8; ++r) {
      const int lrow = wv * 8 + r;
      const int off = lrow * 256 + ((l * 4) ^ ((r & 7) << 4));
      *(unsigned int*)((char*)Bs + off) = pack2(breg[r].x, breg[r].y);
    }
  };
  auto GLOADA = [&](int s, int buf) {
    const int kc = (s < 64) ? s : 63;
    const char* g = (const char*)XbT + (size_t)kc * 65536;
    char* lb = (char*)&As[buf][0];
#pragma unroll
    for (int q = 0; q < 8; ++q) {
      const int chunk = q * 8 + wv;
      gload16(g + chunk * 1024 + l * 16, lb + chunk * 1024);
    }
  };

  f32x4 acc[4][2] = {};
  const int sw = (l & 7) << 4;
  const int lq16 = ((l >> 4) & 3) * 16;

  auto COMPUTE = [&](int buf) {
    const char* a_ = (const char*)&As[buf][0];
    const char* b_ = (const char*)Bs;
#pragma unroll
    for (int ks = 0; ks < 4; ++ks) {
      bf16x8 bf[2];
#pragma unroll
      for (int j = 0; j < 2; ++j) {
        const int n = wc * 32 + j * 16 + lm;
        bf[j] = *(const bf16x8*)(b_ + n * 256 + ((ks * 64 + lq16) ^ sw));
      }
#pragma unroll
      for (int i = 0; i < 4; ++i) {
        const int m = wr * 64 + i * 16 + lm;
        bf16x8 a = *(const bf16x8*)(a_ + m * 256 + ((ks * 64 + lq16) ^ sw));
        acc[i][0] = __builtin_amdgcn_mfma_f32_16x16x32_bf16(a, bf[0], acc[i][0], 0, 0, 0);
        acc[i][1] = __builtin_amdgcn_mfma_f32_16x16x32_bf16(a, bf[1], acc[i][1], 0, 0, 0);
      }
    }
  };

#define WAITV(n) { asm volatile("s_waitcnt vmcnt(" #n ")" ::: "memory"); \
                   __builtin_amdgcn_sched_barrier(0); }
#define WAITL    { asm volatile("s_waitcnt lgkmcnt(0)" ::: "memory"); \
                   __builtin_amdgcn_sched_barrier(0); }

  RLOADB(0); GLOADA(0, 0);
  WAITV(0)
  SWRITE();
  RLOADB(1); GLOADA(1, 1);
  WAITL
  __builtin_amdgcn_s_barrier();

  for (int s = 0; s < 64; ++s) {
    COMPUTE(s & 1);
    if (s == 63) break;
    WAITV(8)
    __builtin_amdgcn_s_barrier();
    SWRITE();
    RLOADB(s + 2);
    GLOADA(s + 2, s & 1);
    WAITL
    WAITV(16)
    __builtin_amdgcn_s_barrier();
  }
#undef WAITV
#undef WAITL

#pragma unroll
  for (int i = 0; i < 4; ++i) {
    const int r0 = wr * 64 + i * 16 + (l >> 4) * 4;
#pragma unroll
    for (int j = 0; j < 2; ++j) {
      const int col = n0 + wc * 32 + j * 16 + lm;
      const float bb = (col < DIN) ? bias[col] : 0.f;
#pragma unroll
      for (int q = 0; q < 4; ++q) {
        const float v = acc[i][j][q] + bb;
        Out[(size_t)(r0 + q) * KP + col] = (col < DIN) ? (unsigned short)f2b(v) : 0;
      }
    }
  }
}

// ---------------------------------------------------------------------------
__global__ __launch_bounds__(512)
void gemm_logits(const unsigned short* __restrict__ Qbf,
                 const unsigned short* __restrict__ Kbf, float* __restrict__ LP)
{
  const int qr = blockIdx.x & 1, qc = blockIdx.x >> 1, z = blockIdx.z;
  const int tid = threadIdx.x, lane = tid & 63, wv = tid >> 6;
  const int lm = lane & 15, lq = (lane >> 4) * 8;
  const int rowBase = qr * 128 + (wv & 3) * 32;
  const int colBase = qc * 128 + (wv >> 2) * 64;
  const int k0 = z * 128;
  f32x4 acc[2][4] = {};
#pragma unroll
  for (int ks = 0; ks < 4; ++ks) {
    bf16x8 a[2], b[4];
#pragma unroll
    for (int i = 0; i < 2; ++i)
      a[i] = *(const bf16x8*)(Qbf + (size_t)(rowBase + i * 16 + lm) * KP + k0 + ks * 32 + lq);
#pragma unroll
    for (int j = 0; j < 4; ++j)
      b[j] = *(const bf16x8*)(Kbf + (size_t)(colBase + j * 16 + lm) * KP + k0 + ks * 32 + lq);
#pragma unroll
    for (int i = 0; i < 2; ++i)
#pragma unroll
      for (int j = 0; j < 4; ++j)
        acc[i][j] = __builtin_amdgcn_mfma_f32_16x16x32_bf16(a[i], b[j], acc[i][j], 0, 0, 0);
  }
  float* out = LP + (size_t)z * 65536;
#pragma unroll
  for (int i = 0; i < 2; ++i) {
    const int r0 = rowBase + i * 16 + (lane >> 4) * 4;
#pragma unroll
    for (int j = 0; j < 4; ++j) {
      const int col = colBase + j * 16 + lm;
#pragma unroll
      for (int q = 0; q < 4; ++q)
        out[(size_t)(r0 + q) * 256 + col] = acc[i][j][q];
    }
  }
}

// ---------------------------------------------------------------------------
__global__ void softmax_fused(const float* __restrict__ LP, float* __restrict__ abar)
{
  __shared__ float red[8];
  const int m = blockIdx.x, t = threadIdx.x;
  float v = 0.f;
#pragma unroll 8
  for (int zz = 0; zz < 64; ++zz) v += LP[(size_t)zz * 65536 + m * 256 + t];
  const float scale = 1.0f / sqrtf((float)DIN);
  float mx = v;
#pragma unroll
  for (int o = 32; o >= 1; o >>= 1) mx = fmaxf(mx, __shfl_xor(mx, o, 64));
  if ((t & 63) == 0) red[t >> 6] = mx;
  __syncthreads();
  mx = fmaxf(fmaxf(red[0], red[1]), fmaxf(red[2], red[3]));
  float e = __expf((v - mx) * scale);
  float s = e;
#pragma unroll
  for (int o = 32; o >= 1; o >>= 1) s += __shfl_xor(s, o, 64);
  if ((t & 63) == 0) red[4 + (t >> 6)] = s;
  __syncthreads();
  s = red[4] + red[5] + red[6] + red[7];
  atomicAdd(&abar[t], e * (1.0f / 256.0f) / s);
}

__global__ void y_kernel(const float* __restrict__ X, const float* __restrict__ abar,
                         float* __restrict__ y)
{
  __shared__ float ab[256];
  ab[threadIdx.x] = abar[threadIdx.x];
  __syncthreads();
  const int c = blockIdx.x * 256 + threadIdx.x;
  if (c >= DIN) return;
  float s = 0.f;
#pragma unroll 8
  for (int m = 0; m < 256; ++m) s += ab[m] * X[(size_t)m * DIN + c];
  y[c] = s;
}

__global__ __launch_bounds__(512)
void ctx_mv(const float* __restrict__ Wv, const float* __restrict__ y,
            const float* __restrict__ bv, float* __restrict__ ctx)
{
  const int wv = threadIdx.x >> 6, l = threadIdx.x & 63;
  const int row = blockIdx.x * 8 + wv;
  if (row >= DIN) return;
  const float* wr_ = Wv + (size_t)row * DIN;
  float s = 0.f;
#pragma unroll 4
  for (int it = 0; it < 61; ++it) {
    const int k = it * 128 + l * 2;
    if (k < DIN) {
      float2 w2 = *(const float2*)(wr_ + k);
      float2 y2 = *(const float2*)(y + k);
      s = fmaf(w2.x, y2.x, s);
      s = fmaf(w2.y, y2.y, s);
    }
  }
#pragma unroll
  for (int o = 32; o >= 1; o >>= 1) s += __shfl_xor(s, o, 64);
  if (l == 0) ctx[row] = s + bv[row];
}

__global__ void base_kernel(const float* __restrict__ mu, const float* __restrict__ sg,
                            const float* __restrict__ ep, const float* __restrict__ ctx,
                            float* __restrict__ base)
{
  const int j = threadIdx.x;
  if (j >= HOUT) return;
  const int i0 = blockIdx.x * 31;
  const int i1 = min(i0 + 31, DIN);
  float acc = 0.f;
#pragma unroll 4
  for (int i = i0; i < i1; ++i) {
    const size_t idx = (size_t)i * NNODE + DIN + j;
    acc = fmaf(ctx[i], fmaf(sg[idx], ep[idx], mu[idx]), acc);
  }
  atomicAdd(&base[j], acc);
}

__global__ void ws_kernel(const float* __restrict__ mu, const float* __restrict__ sg,
                          const float* __restrict__ ep, float* __restrict__ WsG)
{
  const int t = blockIdx.x;
  const int j = threadIdx.x;
  if (j >= HOUT) return;
  const size_t idx = (size_t)(DIN + t) * NNODE + DIN + j;
  WsG[t * HOUT + j] = fmaf(sg[idx], ep[idx], mu[idx]);
}

// ---------------------------------------------------------------------------
__global__ __launch_bounds__(64, 1)
void scan2(const float* __restrict__ WsG, const float* __restrict__ base,
           const float* __restrict__ bmu, const float* __restrict__ bsg,
           const float* __restrict__ epb, float* __restrict__ out)
{
  __shared__ __align__(16) float tile[32 * HOUT + 128];
  const int l = threadIdx.x;

  float a0, a1, a2, a3, a4;
  {
    int j = l;       a0 = base[j] + bmu[j] + bsg[j] * epb[j];
    j = l + 64;      a1 = base[j] + bmu[j] + bsg[j] * epb[j];
    j = l + 128;     a2 = base[j] + bmu[j] + bsg[j] * epb[j];
    j = l + 192;     a3 = base[j] + bmu[j] + bsg[j] * epb[j];
    j = l + 256;     a4 = (j < HOUT) ? (base[j] + bmu[j] + bsg[j] * epb[j]) : 0.f;
  }

  float4 stg[33];
  auto LOADT = [&](int tb) {
    const int nfl = ((tb == 8) ? 4 : 32) * HOUT;
    const float* src = WsG + tb * 32 * HOUT;
#pragma unroll
    for (int c = 0; c < 33; ++c) {
      const int o = c * 256 + l * 4;
      if (o < nfl) stg[c] = *(const float4*)(src + o);
    }
  };
  auto WRITET = [&](int tb) {
    const int nfl = ((tb == 8) ? 4 : 32) * HOUT;
#pragma unroll
    for (int c = 0; c < 33; ++c) {
      const int o = c * 256 + l * 4;
      if (o < nfl) *(float4*)&tile[o] = stg[c];
    }
  };

  float w0, w1, w2, w3, w4;
  auto PRER = [&](int trow) {
    const float* tr = tile + trow * HOUT;
    w0 = tr[l]; w1 = tr[l + 64]; w2 = tr[l + 128]; w3 = tr[l + 192]; w4 = tr[l + 256];
  };

  auto inner = [&](auto Bc, int tb, int nrows) {
    constexpr int B = Bc.value;
    for (int tt = 0; tt < nrows; ++tt) {
      const int t = tb * 32 + tt;
      float pre;
      if constexpr (B == 0) pre = readlane_f(a0, t & 63);
      else if constexpr (B == 1) pre = readlane_f(a1, t & 63);
      else if constexpr (B == 2) pre = readlane_f(a2, t & 63);
      else if constexpr (B == 3) pre = readlane_f(a3, t & 63);
      else pre = readlane_f(a4, t & 63);
      const float pc = fminf(fmaxf(pre, -12.f), 12.f);
      const float e = __expf(2.f * pc);
      const float vt = 1.f - 2.f / (e + 1.f);
      if (t >= 256 && l == 0) out[t - 256] = vt;
      if (l > t)            a0 = fmaf(vt, w0, a0);
      if (l + 64 > t)       a1 = fmaf(vt, w1, a1);
      if (l + 128 > t)      a2 = fmaf(vt, w2, a2);
      if (l + 192 > t)      a3 = fmaf(vt, w3, a3);
      if (l + 256 > t && l + 256 < HOUT) a4 = fmaf(vt, w4, a4);
      if (tt + 1 < nrows) PRER(tt + 1);
    }
  };

  LOADT(0); WRITET(0); PRER(0);

#define TILE_STEP(tb, B, nr)                                    \
  { if ((tb) < 8) LOADT((tb) + 1);                              \
    inner(std::integral_constant<int, B>{}, (tb), (nr));        \
    if ((tb) < 8) { WRITET((tb) + 1); PRER(0); } }

  TILE_STEP(0, 0, 32)
  TILE_STEP(1, 0, 32)
  TILE_STEP(2, 1, 32)
  TILE_STEP(3, 1, 32)
  TILE_STEP(4, 2, 32)
  TILE_STEP(5, 2, 32)
  TILE_STEP(6, 3, 32)
  TILE_STEP(7, 3, 32)
  TILE_STEP(8, 4, 4)
#undef TILE_STEP
}

// ---------------------------------------------------------------------------
extern "C" void kernel_launch(void* const* d_in, const int* in_sizes, int n_in,
                              void* d_out, int out_size, void* d_ws, size_t ws_size,
                              hipStream_t stream)
{
  const float* X   = (const float*)d_in[0];
  const float* Wq  = (const float*)d_in[1];
  const float* bq  = (const float*)d_in[2];
  const float* Wk  = (const float*)d_in[3];
  const float* bk  = (const float*)d_in[4];
  const float* Wv  = (const float*)d_in[5];
  const float* bv  = (const float*)d_in[6];
  const float* wmu = (const float*)d_in[7];
  const float* wsg = (const float*)d_in[8];
  const float* bmu = (const float*)d_in[9];
  const float* bsg = (const float*)d_in[10];
  const float* epw = (const float*)d_in[11];
  const float* epb = (const float*)d_in[12];

  char* p = (char*)d_ws;
  auto alloc = [&](size_t bytes) -> char* {
    char* r = p;
    p += (bytes + 255) & ~(size_t)255;
    return r;
  };
  unsigned short* XbT = (unsigned short*)alloc((size_t)64 * 65536);
  unsigned short* Qbf = (unsigned short*)alloc((size_t)256 * KP * 2);
  unsigned short* Kbf = (unsigned short*)alloc((size_t)256 * KP * 2);
  float* LP    = (float*)alloc((size_t)64 * 65536 * 4);
  float* abar  = (float*)alloc(256 * 4);
  float* y     = (float*)alloc(7686 * 4);
  float* ctx   = (float*)alloc(7686 * 4);
  float* base  = (float*)alloc(HOUT * 4);
  float* WsG   = (float*)alloc((size_t)HOUT * HOUT * 4 + 1024);
  float* prb   = (float*)alloc(65536);   // probe sinks

  prep_x<<<dim3(256), dim3(256), 0, stream>>>(X, XbT);
  hipMemsetAsync(abar, 0, 256 * 4, stream);
  hipMemsetAsync(base, 0, HOUT * 4, stream);
  hipMemsetAsync(Qbf, 0, (size_t)256 * KP * 2, stream);
  hipMemsetAsync(Kbf, 0, (size_t)256 * KP * 2, stream);

  // --- probes (diagnostic round): same data, two access patterns ---
  probe_f4 <<<dim3(2048), dim3(256), 0, stream>>>(Wq, prb);
  probe_f2s<<<dim3(241, 1, 4), dim3(512), 0, stream>>>(Wk, prb + 8192);

  gemm_qk2<<<dim3(121, 2), dim3(512), 0, stream>>>(XbT, Wq, Wk, bq, bk, Qbf, Kbf);
  gemm_logits<<<dim3(4, 1, 64), dim3(512), 0, stream>>>(Qbf, Kbf, LP);
  softmax_fused<<<dim3(256), dim3(256), 0, stream>>>(LP, abar);
  y_kernel<<<dim3(31), dim3(256), 0, stream>>>(X, abar, y);
  ctx_mv<<<dim3(961), dim3(512), 0, stream>>>(Wv, y, bv, ctx);
  base_kernel<<<dim3(256), dim3(320), 0, stream>>>(wmu, wsg, epw, ctx, base);
  ws_kernel<<<dim3(260), dim3(320), 0, stream>>>(wmu, wsg, epw, WsG);
  scan2<<<dim3(1), dim3(64), 0, stream>>>(WsG, base, bmu, bsg, epb, (float*)d_out);
}

// Round 11
// 445.678 us; speedup vs baseline: 1.1795x; 1.1795x over previous
//
#include <hip/hip_runtime.h>
#include <hip/hip_bf16.h>
#include <type_traits>

#define DIN   7686
#define NNODE 7946
#define HOUT  260
#define KP    8192   // padded k (64 kc-blocks of 128)

typedef __attribute__((ext_vector_type(8))) short bf16x8;
typedef __attribute__((ext_vector_type(4))) float f32x4;

__device__ __forceinline__ unsigned int f2b(float f) {
  union { float f; unsigned int u; } v; v.f = f;
  return (v.u + 0x7FFFu + ((v.u >> 16) & 1u)) >> 16;  // RNE float->bf16
}
__device__ __forceinline__ unsigned int pack2(float lo, float hi) {
  unsigned int r;
  asm("v_cvt_pk_bf16_f32 %0, %1, %2" : "=v"(r) : "v"(lo), "v"(hi));
  return r;
}
__device__ __forceinline__ float b2f(unsigned short h) {
  union { unsigned int u; float f; } v; v.u = ((unsigned int)h) << 16; return v.f;
}
__device__ __forceinline__ float readlane_f(float v, int lane) {
  return __uint_as_float(__builtin_amdgcn_readlane(__float_as_uint(v), lane));
}

// ---------------------------------------------------------------------------
// prep_x2 (R7/R9 verified): fp32 X -> bf16 FRAGMENT-MAJOR for direct MFMA
// A-loads: block(kc 0..63, i16 0..15, ks 0..3) = 1KB at ((kc*16+i16)*4+ks)*1024
// lane l: m = i16*16 + (l&15), k = kc*128 + ks*32 + (l>>4)*8 .. +8. Pads zero.
// ---------------------------------------------------------------------------
__global__ void prep_x2(const float* __restrict__ X, char* __restrict__ XbT2)
{
  const int m = blockIdx.x, t = threadIdx.x;
  const float* row = X + (size_t)m * DIN;
  const int i16 = m >> 4;
#pragma unroll
  for (int c2 = 0; c2 < 4; ++c2) {
    const int k8 = (c2 * 256 + t) * 8;
    float f[8];
    if (k8 + 8 <= DIN) {
#pragma unroll
      for (int h = 0; h < 4; ++h) {
        float2 v = *(const float2*)(row + k8 + h * 2);
        f[h * 2] = v.x; f[h * 2 + 1] = v.y;
      }
    } else {
#pragma unroll
      for (int h = 0; h < 8; ++h) f[h] = (k8 + h < DIN) ? row[k8 + h] : 0.f;
    }
    uint4 o;
    o.x = pack2(f[0], f[1]); o.y = pack2(f[2], f[3]);
    o.z = pack2(f[4], f[5]); o.w = pack2(f[6], f[7]);
    const int kc = k8 >> 7, kk = k8 & 127, ks = kk >> 5, hq = (kk & 31) >> 3;
    const int lane = (m & 15) + (hq << 4);
    char* dst = XbT2 + ((((size_t)kc * 16 + i16) * 4 + ks) << 10) + lane * 16;
    *(uint4*)dst = o;
  }
}

// ---------------------------------------------------------------------------
// gemm_qk6: fabric-minimal GEMM. BM=256, BN=256, BK=32, k-split x4.
// 1D grid 248 = 31 n-tiles x (2 mats x 4 z); wgid&7 = mat*4+z so each XCD
// hosts one (mat,z): its 31 WGs share the same A k-slice (L2-resident).
// A: fragment-direct global loads from XbT2 (no LDS). B: 2-deep named reg
// ring -> padded LDS [256][40] (x2 dbuf, 40KB), ONE barrier/step,
// counted vmcnt(12) only (never drains).
// Out: bf16 partials PQK[(mat*4+z)][256][KP].
// ---------------------------------------------------------------------------
__global__ __launch_bounds__(512, 2)
void gemm_qk6(const char* __restrict__ XbT2,
              const float* __restrict__ Wq, const float* __restrict__ Wk,
              unsigned short* __restrict__ PQK)
{
  const int wgid = blockIdx.x;
  const int mz = wgid & 7, mat = mz >> 2, z = mz & 3;
  const int nt = wgid >> 3, n0 = nt * 256;
  const float* W = mat ? Wk : Wq;
  const int tid = threadIdx.x, l = tid & 63, wv = tid >> 6;
  const int wr = wv >> 2, wc = wv & 3;          // 2 row-bands x 4 col-bands
  const int lm = l & 15, hq = l >> 4;

  __shared__ __align__(16) unsigned short Bs[2][256 * 40];  // 2 x 20KB

  // B staging: thread -> row tid>>1 (256 rows), 16 k-floats at (tid&1)*16
  const int brow = tid >> 1, kh = tid & 1;
  int bn = n0 + brow; if (bn > DIN - 1) bn = DIN - 1;
  const long long bbase = (long long)bn * DIN;
  const long long DD = (long long)DIN * DIN;
  const int sBase = z * 61;                     // 61 BK=32 steps per quarter

  float4 sa0, sa1, sa2, sa3;   // ring set A
  float4 sb0, sb1, sb2, sb3;   // ring set B

#define LOADB(S0_, S1_, S2_, S3_, t_) {                                 \
    int tt_ = (t_); if (tt_ > 60) tt_ = 60;                             \
    const int kg_ = (sBase + tt_) * 32 + kh * 16;                       \
    const long long kb_ = bbase + kg_;                                  \
    if (kb_ + 16 <= DD) {                                               \
      S0_ = *(const float4*)(W + kb_);                                  \
      S1_ = *(const float4*)(W + kb_ + 4);                              \
      S2_ = *(const float4*)(W + kb_ + 8);                              \
      S3_ = *(const float4*)(W + kb_ + 12);                             \
    } else {                                                            \
      float f_[16];                                                     \
      _Pragma("unroll")                                                 \
      for (int h_ = 0; h_ < 16; ++h_)                                   \
        f_[h_] = (kg_ + h_ < DIN) ? W[bbase + kg_ + h_] : 0.f;          \
      S0_ = make_float4(f_[0], f_[1], f_[2], f_[3]);                    \
      S1_ = make_float4(f_[4], f_[5], f_[6], f_[7]);                    \
      S2_ = make_float4(f_[8], f_[9], f_[10], f_[11]);                  \
      S3_ = make_float4(f_[12], f_[13], f_[14], f_[15]);                \
    } }

#define SWRITE(buf_, S0_, S1_, S2_, S3_) {                              \
    uint4 o0_, o1_;                                                     \
    o0_.x = pack2(S0_.x, S0_.y); o0_.y = pack2(S0_.z, S0_.w);           \
    o0_.z = pack2(S1_.x, S1_.y); o0_.w = pack2(S1_.z, S1_.w);           \
    o1_.x = pack2(S2_.x, S2_.y); o1_.y = pack2(S2_.z, S2_.w);           \
    o1_.z = pack2(S3_.x, S3_.y); o1_.w = pack2(S3_.z, S3_.w);           \
    char* p_ = (char*)Bs[buf_] + brow * 80 + kh * 32;                   \
    *(uint4*)p_ = o0_; *(uint4*)(p_ + 16) = o1_; }

  f32x4 acc[8][4] = {};

#define COMPUTE(buf_, sg_) {                                            \
    const int kc_ = (sg_) >> 2, ks_ = (sg_) & 3;                        \
    const char* bs_ = (const char*)Bs[buf_];                            \
    bf16x8 bfr_[4];                                                     \
    _Pragma("unroll")                                                   \
    for (int j_ = 0; j_ < 4; ++j_) {                                    \
      const int n_ = wc * 64 + j_ * 16 + lm;                            \
      bfr_[j_] = *(const bf16x8*)(bs_ + n_ * 80 + hq * 16);             \
    }                                                                   \
    _Pragma("unroll")                                                   \
    for (int i_ = 0; i_ < 8; ++i_) {                                    \
      bf16x8 a_ = *(const bf16x8*)(XbT2 +                               \
        ((((size_t)kc_ * 16 + (wr * 8 + i_)) * 4 + ks_) << 10) + l * 16); \
      acc[i_][0] = __builtin_amdgcn_mfma_f32_16x16x32_bf16(a_, bfr_[0], acc[i_][0], 0, 0, 0); \
      acc[i_][1] = __builtin_amdgcn_mfma_f32_16x16x32_bf16(a_, bfr_[1], acc[i_][1], 0, 0, 0); \
      acc[i_][2] = __builtin_amdgcn_mfma_f32_16x16x32_bf16(a_, bfr_[2], acc[i_][2], 0, 0, 0); \
      acc[i_][3] = __builtin_amdgcn_mfma_f32_16x16x32_bf16(a_, bfr_[3], acc[i_][3], 0, 0, 0); \
    } }

#define SB_()    __builtin_amdgcn_sched_barrier(0)
#define WAITV(n) { asm volatile("s_waitcnt vmcnt(" #n ")" ::: "memory"); SB_(); }
#define WAITL()  { asm volatile("s_waitcnt lgkmcnt(0)" ::: "memory"); SB_(); }
#define BARRIER() { __builtin_amdgcn_s_barrier(); SB_(); }

  // prologue: buf0 <- step 0 (via SB-set temp); SA <- step 1; SB <- step 2
  LOADB(sb0, sb1, sb2, sb3, 0)
  LOADB(sa0, sa1, sa2, sa3, 1)
  WAITV(4)
  SWRITE(0, sb0, sb1, sb2, sb3)
  LOADB(sb0, sb1, sb2, sb3, 2)
  WAITL()
  BARRIER()

  // steady state: one barrier/step; vmcnt(12) leaves next-next B + A in flight
  for (int s = 0; s < 60; s += 2) {
    // even step s: consume SA (holds s+1)
    COMPUTE(0, sBase + s)
    WAITV(12)
    SWRITE(1, sa0, sa1, sa2, sa3)
    LOADB(sa0, sa1, sa2, sa3, s + 3)
    WAITL()
    BARRIER()
    // odd step s+1: consume SB (holds s+2)
    COMPUTE(1, sBase + s + 1)
    WAITV(12)
    SWRITE(0, sb0, sb1, sb2, sb3)
    LOADB(sb0, sb1, sb2, sb3, s + 4)
    WAITL()
    BARRIER()
  }
  COMPUTE(0, sBase + 60)   // final step (buf 60&1 = 0)

#undef LOADB
#undef SWRITE
#undef COMPUTE
#undef WAITV
#undef WAITL
#undef BARRIER
#undef SB_

  // epilogue: bf16 partial store for this (mat, z)
  unsigned short* Cp = PQK + (size_t)mz * 256 * KP;
#pragma unroll
  for (int i = 0; i < 8; ++i) {
    const int r0 = wr * 128 + i * 16 + hq * 4;
#pragma unroll
    for (int j = 0; j < 4; ++j) {
      const int col = n0 + wc * 64 + j * 16 + lm;
#pragma unroll
      for (int q = 0; q < 4; ++q)
        Cp[(size_t)(r0 + q) * KP + col] = (unsigned short)f2b(acc[i][j][q]);
    }
  }
}

// ---------------------------------------------------------------------------
// reduce_qk4 (R9 verified): sum 4 bf16 partials + bias -> Qbf/Kbf, pads zero
// ---------------------------------------------------------------------------
__global__ void reduce_qk4(const unsigned short* __restrict__ PQK,
                           const float* __restrict__ bq, const float* __restrict__ bk,
                           unsigned short* __restrict__ Qbf, unsigned short* __restrict__ Kbf)
{
  const int mat = blockIdx.y;
  const int c = blockIdx.x * 128 + threadIdx.x;
  const float* bias = mat ? bk : bq;
  const bool valid = c < DIN;
  const float bb = valid ? bias[c] : 0.f;
  const unsigned short* P0 = PQK + ((size_t)(mat * 4 + 0) * 256) * KP + c;
  const unsigned short* P1 = PQK + ((size_t)(mat * 4 + 1) * 256) * KP + c;
  const unsigned short* P2 = PQK + ((size_t)(mat * 4 + 2) * 256) * KP + c;
  const unsigned short* P3 = PQK + ((size_t)(mat * 4 + 3) * 256) * KP + c;
  unsigned short* O = (mat ? Kbf : Qbf) + c;
#pragma unroll 4
  for (int r = 0; r < 256; ++r) {
    float v = b2f(P0[(size_t)r * KP]) + b2f(P1[(size_t)r * KP]) +
              b2f(P2[(size_t)r * KP]) + b2f(P3[(size_t)r * KP]) + bb;
    if (!valid) v = 0.f;
    O[(size_t)r * KP] = (unsigned short)f2b(v);
  }
}

// ---------------------------------------------------------------------------
// logits partials (R9 verified): LP[z][m][n] over 512-k chunks, grid (4,1,16)
// ---------------------------------------------------------------------------
__global__ __launch_bounds__(512)
void gemm_logits(const unsigned short* __restrict__ Qbf,
                 const unsigned short* __restrict__ Kbf, float* __restrict__ LP)
{
  const int qr = blockIdx.x & 1, qc = blockIdx.x >> 1, z = blockIdx.z;
  const int tid = threadIdx.x, lane = tid & 63, wv = tid >> 6;
  const int lm = lane & 15, lq = (lane >> 4) * 8;
  const int rowBase = qr * 128 + (wv & 3) * 32;
  const int colBase = qc * 128 + (wv >> 2) * 64;
  const int k0 = z * 512;
  f32x4 acc[2][4] = {};
#pragma unroll 4
  for (int ks = 0; ks < 16; ++ks) {
    bf16x8 a[2], b[4];
#pragma unroll
    for (int i = 0; i < 2; ++i)
      a[i] = *(const bf16x8*)(Qbf + (size_t)(rowBase + i * 16 + lm) * KP + k0 + ks * 32 + lq);
#pragma unroll
    for (int j = 0; j < 4; ++j)
      b[j] = *(const bf16x8*)(Kbf + (size_t)(colBase + j * 16 + lm) * KP + k0 + ks * 32 + lq);
#pragma unroll
    for (int i = 0; i < 2; ++i)
#pragma unroll
      for (int j = 0; j < 4; ++j)
        acc[i][j] = __builtin_amdgcn_mfma_f32_16x16x32_bf16(a[i], b[j], acc[i][j], 0, 0, 0);
  }
  float* out = LP + (size_t)z * 65536;
#pragma unroll
  for (int i = 0; i < 2; ++i) {
    const int r0 = rowBase + i * 16 + (lane >> 4) * 4;
#pragma unroll
    for (int j = 0; j < 4; ++j) {
      const int col = colBase + j * 16 + lm;
#pragma unroll
      for (int q = 0; q < 4; ++q)
        out[(size_t)(r0 + q) * 256 + col] = acc[i][j][q];
    }
  }
}

// ---------------------------------------------------------------------------
// fused: sum 16 logit partials -> row softmax -> atomicAdd into abar (w/ 1/256)
// ---------------------------------------------------------------------------
__global__ void softmax_fused(const float* __restrict__ LP, float* __restrict__ abar)
{
  __shared__ float red[8];
  const int m = blockIdx.x, t = threadIdx.x;
  float v = 0.f;
#pragma unroll
  for (int zz = 0; zz < 16; ++zz) v += LP[(size_t)zz * 65536 + m * 256 + t];
  const float scale = 1.0f / sqrtf((float)DIN);
  float mx = v;
#pragma unroll
  for (int o = 32; o >= 1; o >>= 1) mx = fmaxf(mx, __shfl_xor(mx, o, 64));
  if ((t & 63) == 0) red[t >> 6] = mx;
  __syncthreads();
  mx = fmaxf(fmaxf(red[0], red[1]), fmaxf(red[2], red[3]));
  float e = __expf((v - mx) * scale);
  float s = e;
#pragma unroll
  for (int o = 32; o >= 1; o >>= 1) s += __shfl_xor(s, o, 64);
  if ((t & 63) == 0) red[4 + (t >> 6)] = s;
  __syncthreads();
  s = red[4] + red[5] + red[6] + red[7];
  atomicAdd(&abar[t], e * (1.0f / 256.0f) / s);
}

// y[c] = sum_m abar[m] * X[m][c]
__global__ void y_kernel(const float* __restrict__ X, const float* __restrict__ abar,
                         float* __restrict__ y)
{
  __shared__ float ab[256];
  ab[threadIdx.x] = abar[threadIdx.x];
  __syncthreads();
  const int c = blockIdx.x * 256 + threadIdx.x;
  if (c >= DIN) return;
  float s = 0.f;
#pragma unroll 8
  for (int m = 0; m < 256; ++m) s += ab[m] * X[(size_t)m * DIN + c];
  y[c] = s;
}

// ctx[d] = Wv[d,:]·y + bv[d] — one row per wave, lane-contiguous stream
__global__ __launch_bounds__(512)
void ctx_mv(const float* __restrict__ Wv, const float* __restrict__ y,
            const float* __restrict__ bv, float* __restrict__ ctx)
{
  const int wv = threadIdx.x >> 6, l = threadIdx.x & 63;
  const int row = blockIdx.x * 8 + wv;
  if (row >= DIN) return;
  const float* wr_ = Wv + (size_t)row * DIN;
  float s = 0.f;
#pragma unroll 4
  for (int it = 0; it < 61; ++it) {
    const int k = it * 128 + l * 2;
    if (k < DIN) {
      float2 w2 = *(const float2*)(wr_ + k);
      float2 y2 = *(const float2*)(y + k);
      s = fmaf(w2.x, y2.x, s);
      s = fmaf(w2.y, y2.y, s);
    }
  }
#pragma unroll
  for (int o = 32; o >= 1; o >>= 1) s += __shfl_xor(s, o, 64);
  if (l == 0) ctx[row] = s + bv[row];
}

// base[j] += sum_{i in chunk} ctx[i] * (mu+sg*ep)[i][DIN+j]
__global__ void base_kernel(const float* __restrict__ mu, const float* __restrict__ sg,
                            const float* __restrict__ ep, const float* __restrict__ ctx,
                            float* __restrict__ base)
{
  const int j = threadIdx.x;
  if (j >= HOUT) return;
  const int i0 = blockIdx.x * 31;
  const int i1 = min(i0 + 31, DIN);
  float acc = 0.f;
#pragma unroll 4
  for (int i = i0; i < i1; ++i) {
    const size_t idx = (size_t)i * NNODE + DIN + j;
    acc = fmaf(ctx[i], fmaf(sg[idx], ep[idx], mu[idx]), acc);
  }
  atomicAdd(&base[j], acc);
}

// WsG[t][j] = (mu+sg*ep)[DIN+t][DIN+j]
__global__ void ws_kernel(const float* __restrict__ mu, const float* __restrict__ sg,
                          const float* __restrict__ ep, float* __restrict__ WsG)
{
  const int t = blockIdx.x;
  const int j = threadIdx.x;
  if (j >= HOUT) return;
  const size_t idx = (size_t)(DIN + t) * NNODE + DIN + j;
  WsG[t * HOUT + j] = fmaf(sg[idx], ep[idx], mu[idx]);
}

// ---------------------------------------------------------------------------
// scan2 (R6 verified): latency-minimal sequential NEAT scan. 1 wave.
// ---------------------------------------------------------------------------
__global__ __launch_bounds__(64, 1)
void scan2(const float* __restrict__ WsG, const float* __restrict__ base,
           const float* __restrict__ bmu, const float* __restrict__ bsg,
           const float* __restrict__ epb, float* __restrict__ out)
{
  __shared__ __align__(16) float tile[32 * HOUT + 128];
  const int l = threadIdx.x;

  float a0, a1, a2, a3, a4;
  {
    int j = l;       a0 = base[j] + bmu[j] + bsg[j] * epb[j];
    j = l + 64;      a1 = base[j] + bmu[j] + bsg[j] * epb[j];
    j = l + 128;     a2 = base[j] + bmu[j] + bsg[j] * epb[j];
    j = l + 192;     a3 = base[j] + bmu[j] + bsg[j] * epb[j];
    j = l + 256;     a4 = (j < HOUT) ? (base[j] + bmu[j] + bsg[j] * epb[j]) : 0.f;
  }

  float4 stg[33];
  auto LOADT = [&](int tb) {
    const int nfl = ((tb == 8) ? 4 : 32) * HOUT;
    const float* src = WsG + tb * 32 * HOUT;
#pragma unroll
    for (int c = 0; c < 33; ++c) {
      const int o = c * 256 + l * 4;
      if (o < nfl) stg[c] = *(const float4*)(src + o);
    }
  };
  auto WRITET = [&](int tb) {
    const int nfl = ((tb == 8) ? 4 : 32) * HOUT;
#pragma unroll
    for (int c = 0; c < 33; ++c) {
      const int o = c * 256 + l * 4;
      if (o < nfl) *(float4*)&tile[o] = stg[c];
    }
  };

  float w0, w1, w2, w3, w4;
  auto PRER = [&](int trow) {
    const float* tr = tile + trow * HOUT;
    w0 = tr[l]; w1 = tr[l + 64]; w2 = tr[l + 128]; w3 = tr[l + 192]; w4 = tr[l + 256];
  };

  auto inner = [&](auto Bc, int tb, int nrows) {
    constexpr int B = Bc.value;
    for (int tt = 0; tt < nrows; ++tt) {
      const int t = tb * 32 + tt;
      float pre;
      if constexpr (B == 0) pre = readlane_f(a0, t & 63);
      else if constexpr (B == 1) pre = readlane_f(a1, t & 63);
      else if constexpr (B == 2) pre = readlane_f(a2, t & 63);
      else if constexpr (B == 3) pre = readlane_f(a3, t & 63);
      else pre = readlane_f(a4, t & 63);
      const float pc = fminf(fmaxf(pre, -12.f), 12.f);
      const float e = __expf(2.f * pc);
      const float vt = 1.f - 2.f / (e + 1.f);
      if (t >= 256 && l == 0) out[t - 256] = vt;
      if (l > t)            a0 = fmaf(vt, w0, a0);
      if (l + 64 > t)       a1 = fmaf(vt, w1, a1);
      if (l + 128 > t)      a2 = fmaf(vt, w2, a2);
      if (l + 192 > t)      a3 = fmaf(vt, w3, a3);
      if (l + 256 > t && l + 256 < HOUT) a4 = fmaf(vt, w4, a4);
      if (tt + 1 < nrows) PRER(tt + 1);
    }
  };

  LOADT(0); WRITET(0); PRER(0);

#define TILE_STEP(tb, B, nr)                                    \
  { if ((tb) < 8) LOADT((tb) + 1);                              \
    inner(std::integral_constant<int, B>{}, (tb), (nr));        \
    if ((tb) < 8) { WRITET((tb) + 1); PRER(0); } }

  TILE_STEP(0, 0, 32)
  TILE_STEP(1, 0, 32)
  TILE_STEP(2, 1, 32)
  TILE_STEP(3, 1, 32)
  TILE_STEP(4, 2, 32)
  TILE_STEP(5, 2, 32)
  TILE_STEP(6, 3, 32)
  TILE_STEP(7, 3, 32)
  TILE_STEP(8, 4, 4)
#undef TILE_STEP
}

// ---------------------------------------------------------------------------
extern "C" void kernel_launch(void* const* d_in, const int* in_sizes, int n_in,
                              void* d_out, int out_size, void* d_ws, size_t ws_size,
                              hipStream_t stream)
{
  const float* X   = (const float*)d_in[0];
  const float* Wq  = (const float*)d_in[1];
  const float* bq  = (const float*)d_in[2];
  const float* Wk  = (const float*)d_in[3];
  const float* bk  = (const float*)d_in[4];
  const float* Wv  = (const float*)d_in[5];
  const float* bv  = (const float*)d_in[6];
  const float* wmu = (const float*)d_in[7];
  const float* wsg = (const float*)d_in[8];
  const float* bmu = (const float*)d_in[9];
  const float* bsg = (const float*)d_in[10];
  const float* epw = (const float*)d_in[11];
  const float* epb = (const float*)d_in[12];

  char* p = (char*)d_ws;
  auto alloc = [&](size_t bytes) -> char* {
    char* r = p;
    p += (bytes + 255) & ~(size_t)255;
    return r;
  };
  char* XbT2 = alloc((size_t)64 * 65536);                                  // 4MB
  unsigned short* PQK = (unsigned short*)alloc((size_t)8 * 256 * KP * 2);  // 32MB
  unsigned short* Qbf = (unsigned short*)alloc((size_t)256 * KP * 2);      // 4MB
  unsigned short* Kbf = (unsigned short*)alloc((size_t)256 * KP * 2);      // 4MB
  float* LP   = (float*)alloc((size_t)16 * 65536 * 4);                     // 4MB
  float* abar = (float*)alloc(256 * 4);
  float* y    = (float*)alloc(7686 * 4);
  float* ctx  = (float*)alloc(7686 * 4);
  float* base = (float*)alloc(HOUT * 4);
  float* WsG  = (float*)alloc((size_t)HOUT * HOUT * 4 + 1024);

  prep_x2<<<dim3(256), dim3(256), 0, stream>>>(X, XbT2);
  hipMemsetAsync(abar, 0, 256 * 4, stream);
  hipMemsetAsync(base, 0, HOUT * 4, stream);

  gemm_qk6<<<dim3(248), dim3(512), 0, stream>>>(XbT2, Wq, Wk, PQK);
  reduce_qk4<<<dim3(64, 2), dim3(128), 0, stream>>>(PQK, bq, bk, Qbf, Kbf);
  gemm_logits<<<dim3(4, 1, 16), dim3(512), 0, stream>>>(Qbf, Kbf, LP);
  softmax_fused<<<dim3(256), dim3(256), 0, stream>>>(LP, abar);
  y_kernel<<<dim3(31), dim3(256), 0, stream>>>(X, abar, y);
  ctx_mv<<<dim3(961), dim3(512), 0, stream>>>(Wv, y, bv, ctx);
  base_kernel<<<dim3(256), dim3(320), 0, stream>>>(wmu, wsg, epw, ctx, base);
  ws_kernel<<<dim3(260), dim3(320), 0, stream>>>(wmu, wsg, epw, WsG);
  scan2<<<dim3(1), dim3(64), 0, stream>>>(WsG, base, bmu, bsg, epb, (float*)d_out);
}

// Round 13
// 401.987 us; speedup vs baseline: 1.3077x; 1.1087x over previous
//
#include <hip/hip_runtime.h>
#include <hip/hip_bf16.h>
#include <type_traits>

#define DIN   7686
#define NNODE 7946
#define HOUT  260
#define KP    8192   // padded k (64 kc-blocks of 128)
#define BROW  1036   // panel row stride in shorts (1024 + 12 pad -> 2-way banks)

typedef __attribute__((ext_vector_type(8))) short bf16x8;
typedef __attribute__((ext_vector_type(4))) float f32x4;
typedef __attribute__((ext_vector_type(2))) float f32x2;   // native vec for nontemporal

__device__ __forceinline__ unsigned int f2b(float f) {
  union { float f; unsigned int u; } v; v.f = f;
  return (v.u + 0x7FFFu + ((v.u >> 16) & 1u)) >> 16;  // RNE float->bf16
}
__device__ __forceinline__ unsigned int pack2(float lo, float hi) {
  unsigned int r;
  asm("v_cvt_pk_bf16_f32 %0, %1, %2" : "=v"(r) : "v"(lo), "v"(hi));
  return r;
}
__device__ __forceinline__ float b2f(unsigned short h) {
  union { unsigned int u; float f; } v; v.u = ((unsigned int)h) << 16; return v.f;
}
__device__ __forceinline__ float readlane_f(float v, int lane) {
  return __uint_as_float(__builtin_amdgcn_readlane(__float_as_uint(v), lane));
}

// ---------------------------------------------------------------------------
// prep_x2 (verified R7-R11): fp32 X -> bf16 FRAGMENT-MAJOR for direct MFMA
// A-loads: block(kc 0..63, i16 0..15, ks 0..3) = 1KB at ((kc*16+i16)*4+ks)*1024
// lane l: m = i16*16 + (l&15), k = kc*128 + ks*32 + (l>>4)*8 .. +8. Pads zero.
// ---------------------------------------------------------------------------
__global__ void prep_x2(const float* __restrict__ X, char* __restrict__ XbT2)
{
  const int m = blockIdx.x, t = threadIdx.x;
  const float* row = X + (size_t)m * DIN;
  const int i16 = m >> 4;
#pragma unroll
  for (int c2 = 0; c2 < 4; ++c2) {
    const int k8 = (c2 * 256 + t) * 8;
    float f[8];
    if (k8 + 8 <= DIN) {
#pragma unroll
      for (int h = 0; h < 4; ++h) {
        float2 v = *(const float2*)(row + k8 + h * 2);
        f[h * 2] = v.x; f[h * 2 + 1] = v.y;
      }
    } else {
#pragma unroll
      for (int h = 0; h < 8; ++h) f[h] = (k8 + h < DIN) ? row[k8 + h] : 0.f;
    }
    uint4 o;
    o.x = pack2(f[0], f[1]); o.y = pack2(f[2], f[3]);
    o.z = pack2(f[4], f[5]); o.w = pack2(f[6], f[7]);
    const int kc = k8 >> 7, kk = k8 & 127, ks = kk >> 5, hq = (kk & 31) >> 3;
    const int lane = (m & 15) + (hq << 4);
    char* dst = XbT2 + ((((size_t)kc * 16 + i16) * 4 + ks) << 10) + lane * 16;
    *(uint4*)dst = o;
  }
}

// ---------------------------------------------------------------------------
// gemm_qk7: phase-separated panel GEMM.
// WG = 32 W-rows (n-tile) x 2 k-eighths (z = zg, zg+4), 512 thr = 8 waves.
// Phase 1 (per chunk): stage 32x1024 W panel -> LDS. Lane-contiguous 512B
//   nontemporal f32x2 loads (pure-W VM queue; no L2 pollution).
// Phase 2: 32 MFMA steps, NO barriers. A-frags from L2-resident XbT2 via a
//   4-step register ring (pure-A VM queue -> compiler-counted waits, no drain).
// acc accumulates across both chunks; bf16 partial per (mat, zg).
// LDS 64.8 KB -> 2 WGs/CU. grid (241, 2, 4) = 1928 WGs.
// ---------------------------------------------------------------------------
__global__ __launch_bounds__(512, 4)
void gemm_qk7(const char* __restrict__ XbT2,
              const float* __restrict__ Wq, const float* __restrict__ Wk,
              unsigned short* __restrict__ PQK)
{
  const int nt = blockIdx.x, mat = blockIdx.y, zg = blockIdx.z;
  const float* W = mat ? Wk : Wq;
  const int n0 = nt * 32;
  const int tid = threadIdx.x, l = tid & 63, wv = tid >> 6;
  const int lm = l & 15, hq = l >> 4;

  __shared__ __align__(16) unsigned short Bp[32 * BROW];  // 66,304 B

  const long long DD = (long long)DIN * DIN;

  f32x4 acc[2][2] = {};
  bf16x8 A0[2], A1[2], A2[2], A3[2];

#define LA(dst, z_, s_) {                                                 \
    const int kc_ = (z_) * 8 + ((s_) >> 2), ks_ = (s_) & 3;               \
    const char* b_ = XbT2 +                                               \
        ((((size_t)kc_ * 16 + 2 * wv) * 4 + ks_) << 10) + l * 16;         \
    dst[0] = *(const bf16x8*)b_;                                          \
    dst[1] = *(const bf16x8*)(b_ + 4096); }

#define STEP(Ar, s_) {                                                    \
    bf16x8 b0_ = *(const bf16x8*)&Bp[lm * BROW + (s_) * 32 + hq * 8];     \
    bf16x8 b1_ = *(const bf16x8*)&Bp[(16 + lm) * BROW + (s_) * 32 + hq * 8]; \
    acc[0][0] = __builtin_amdgcn_mfma_f32_16x16x32_bf16(Ar[0], b0_, acc[0][0], 0, 0, 0); \
    acc[0][1] = __builtin_amdgcn_mfma_f32_16x16x32_bf16(Ar[0], b1_, acc[0][1], 0, 0, 0); \
    acc[1][0] = __builtin_amdgcn_mfma_f32_16x16x32_bf16(Ar[1], b0_, acc[1][0], 0, 0, 0); \
    acc[1][1] = __builtin_amdgcn_mfma_f32_16x16x32_bf16(Ar[1], b1_, acc[1][1], 0, 0, 0); }

#pragma unroll 1
  for (int h = 0; h < 2; ++h) {
    const int z = zg + h * 4;
    const int k0 = z * 1024;

    if (h) __syncthreads();   // all waves done reading Bp before re-stage

    // A prologue for this chunk: issued FIRST (oldest in queue; completes
    // for free while the W panel streams in behind it)
    LA(A0, z, 0) LA(A1, z, 1) LA(A2, z, 2) LA(A3, z, 3)

    // ---- phase 1: stage panel. lane-contiguous 512B runs, nontemporal ----
#pragma unroll
    for (int r = 0; r < 4; ++r) {
      const int lrow = wv * 4 + r;
      int grow = n0 + lrow; if (grow > DIN - 1) grow = DIN - 1;
      const long long gb = (long long)grow * DIN + k0;
      f32x2 f[8];
#pragma unroll
      for (int c = 0; c < 8; ++c) {
        long long gi = gb + c * 128 + l * 2;
        if (gi > DD - 2) gi = DD - 2;   // tail-safe; A pad zeros nullify
        f[c] = __builtin_nontemporal_load((const f32x2*)(W + gi));
      }
      unsigned short* dr = &Bp[lrow * BROW];
#pragma unroll
      for (int c = 0; c < 8; ++c)
        *(unsigned int*)(dr + c * 128 + l * 2) = pack2(f[c][0], f[c][1]);
    }
    __syncthreads();

    // ---- phase 2: 32 steps, no barriers; VM queue = A-loads only ----
#pragma unroll 1
    for (int su = 0; su < 32; su += 4) {
      STEP(A0, su + 0)
      if (su + 4 < 32) LA(A0, z, su + 4)
      STEP(A1, su + 1)
      if (su + 5 < 32) LA(A1, z, su + 5)
      STEP(A2, su + 2)
      if (su + 6 < 32) LA(A2, z, su + 6)
      STEP(A3, su + 3)
      if (su + 7 < 32) LA(A3, z, su + 7)
    }
  }
#undef LA
#undef STEP

  // epilogue: bf16 partial for (mat, zg)
  unsigned short* Cp = PQK + (size_t)(mat * 4 + zg) * 256 * KP;
#pragma unroll
  for (int i = 0; i < 2; ++i) {
    const int r0 = (2 * wv + i) * 16 + hq * 4;
#pragma unroll
    for (int j = 0; j < 2; ++j) {
      const int col = n0 + j * 16 + lm;
#pragma unroll
      for (int q = 0; q < 4; ++q)
        Cp[(size_t)(r0 + q) * KP + col] = (unsigned short)f2b(acc[i][j][q]);
    }
  }
}

// ---------------------------------------------------------------------------
// reduce_qk4 (verified): sum 4 bf16 partials + bias -> Qbf/Kbf, pads zero
// ---------------------------------------------------------------------------
__global__ void reduce_qk4(const unsigned short* __restrict__ PQK,
                           const float* __restrict__ bq, const float* __restrict__ bk,
                           unsigned short* __restrict__ Qbf, unsigned short* __restrict__ Kbf)
{
  const int mat = blockIdx.y;
  const int c = blockIdx.x * 128 + threadIdx.x;
  const float* bias = mat ? bk : bq;
  const bool valid = c < DIN;
  const float bb = valid ? bias[c] : 0.f;
  const unsigned short* P0 = PQK + ((size_t)(mat * 4 + 0) * 256) * KP + c;
  const unsigned short* P1 = PQK + ((size_t)(mat * 4 + 1) * 256) * KP + c;
  const unsigned short* P2 = PQK + ((size_t)(mat * 4 + 2) * 256) * KP + c;
  const unsigned short* P3 = PQK + ((size_t)(mat * 4 + 3) * 256) * KP + c;
  unsigned short* O = (mat ? Kbf : Qbf) + c;
#pragma unroll 4
  for (int r = 0; r < 256; ++r) {
    float v = b2f(P0[(size_t)r * KP]) + b2f(P1[(size_t)r * KP]) +
              b2f(P2[(size_t)r * KP]) + b2f(P3[(size_t)r * KP]) + bb;
    if (!valid) v = 0.f;
    O[(size_t)r * KP] = (unsigned short)f2b(v);
  }
}

// ---------------------------------------------------------------------------
// logits partials (verified): LP[z][m][n] over 512-k chunks, grid (4,1,16)
// ---------------------------------------------------------------------------
__global__ __launch_bounds__(512)
void gemm_logits(const unsigned short* __restrict__ Qbf,
                 const unsigned short* __restrict__ Kbf, float* __restrict__ LP)
{
  const int qr = blockIdx.x & 1, qc = blockIdx.x >> 1, z = blockIdx.z;
  const int tid = threadIdx.x, lane = tid & 63, wv = tid >> 6;
  const int lm = lane & 15, lq = (lane >> 4) * 8;
  const int rowBase = qr * 128 + (wv & 3) * 32;
  const int colBase = qc * 128 + (wv >> 2) * 64;
  const int k0 = z * 512;
  f32x4 acc[2][4] = {};
#pragma unroll 4
  for (int ks = 0; ks < 16; ++ks) {
    bf16x8 a[2], b[4];
#pragma unroll
    for (int i = 0; i < 2; ++i)
      a[i] = *(const bf16x8*)(Qbf + (size_t)(rowBase + i * 16 + lm) * KP + k0 + ks * 32 + lq);
#pragma unroll
    for (int j = 0; j < 4; ++j)
      b[j] = *(const bf16x8*)(Kbf + (size_t)(colBase + j * 16 + lm) * KP + k0 + ks * 32 + lq);
#pragma unroll
    for (int i = 0; i < 2; ++i)
#pragma unroll
      for (int j = 0; j < 4; ++j)
        acc[i][j] = __builtin_amdgcn_mfma_f32_16x16x32_bf16(a[i], b[j], acc[i][j], 0, 0, 0);
  }
  float* out = LP + (size_t)z * 65536;
#pragma unroll
  for (int i = 0; i < 2; ++i) {
    const int r0 = rowBase + i * 16 + (lane >> 4) * 4;
#pragma unroll
    for (int j = 0; j < 4; ++j) {
      const int col = colBase + j * 16 + lm;
#pragma unroll
      for (int q = 0; q < 4; ++q)
        out[(size_t)(r0 + q) * 256 + col] = acc[i][j][q];
    }
  }
}

// ---------------------------------------------------------------------------
// fused: sum 16 logit partials -> row softmax -> atomicAdd into abar (w/ 1/256)
// ---------------------------------------------------------------------------
__global__ void softmax_fused(const float* __restrict__ LP, float* __restrict__ abar)
{
  __shared__ float red[8];
  const int m = blockIdx.x, t = threadIdx.x;
  float v = 0.f;
#pragma unroll
  for (int zz = 0; zz < 16; ++zz) v += LP[(size_t)zz * 65536 + m * 256 + t];
  const float scale = 1.0f / sqrtf((float)DIN);
  float mx = v;
#pragma unroll
  for (int o = 32; o >= 1; o >>= 1) mx = fmaxf(mx, __shfl_xor(mx, o, 64));
  if ((t & 63) == 0) red[t >> 6] = mx;
  __syncthreads();
  mx = fmaxf(fmaxf(red[0], red[1]), fmaxf(red[2], red[3]));
  float e = __expf((v - mx) * scale);
  float s = e;
#pragma unroll
  for (int o = 32; o >= 1; o >>= 1) s += __shfl_xor(s, o, 64);
  if ((t & 63) == 0) red[4 + (t >> 6)] = s;
  __syncthreads();
  s = red[4] + red[5] + red[6] + red[7];
  atomicAdd(&abar[t], e * (1.0f / 256.0f) / s);
}

// y[c] = sum_m abar[m] * X[m][c]
__global__ void y_kernel(const float* __restrict__ X, const float* __restrict__ abar,
                         float* __restrict__ y)
{
  __shared__ float ab[256];
  ab[threadIdx.x] = abar[threadIdx.x];
  __syncthreads();
  const int c = blockIdx.x * 256 + threadIdx.x;
  if (c >= DIN) return;
  float s = 0.f;
#pragma unroll 8
  for (int m = 0; m < 256; ++m) s += ab[m] * X[(size_t)m * DIN + c];
  y[c] = s;
}

// ctx[d] = Wv[d,:]·y + bv[d] — one row per wave, lane-contiguous stream
__global__ __launch_bounds__(512)
void ctx_mv(const float* __restrict__ Wv, const float* __restrict__ y,
            const float* __restrict__ bv, float* __restrict__ ctx)
{
  const int wv = threadIdx.x >> 6, l = threadIdx.x & 63;
  const int row = blockIdx.x * 8 + wv;
  if (row >= DIN) return;
  const float* wr_ = Wv + (size_t)row * DIN;
  float s = 0.f;
#pragma unroll 4
  for (int it = 0; it < 61; ++it) {
    const int k = it * 128 + l * 2;
    if (k < DIN) {
      f32x2 w2 = __builtin_nontemporal_load((const f32x2*)(wr_ + k));
      float2 y2 = *(const float2*)(y + k);
      s = fmaf(w2[0], y2.x, s);
      s = fmaf(w2[1], y2.y, s);
    }
  }
#pragma unroll
  for (int o = 32; o >= 1; o >>= 1) s += __shfl_xor(s, o, 64);
  if (l == 0) ctx[row] = s + bv[row];
}

// base[j] += sum_{i in chunk} ctx[i] * (mu+sg*ep)[i][DIN+j]
__global__ void base_kernel(const float* __restrict__ mu, const float* __restrict__ sg,
                            const float* __restrict__ ep, const float* __restrict__ ctx,
                            float* __restrict__ base)
{
  const int j = threadIdx.x;
  if (j >= HOUT) return;
  const int i0 = blockIdx.x * 31;
  const int i1 = min(i0 + 31, DIN);
  float acc = 0.f;
#pragma unroll 4
  for (int i = i0; i < i1; ++i) {
    const size_t idx = (size_t)i * NNODE + DIN + j;
    acc = fmaf(ctx[i], fmaf(sg[idx], ep[idx], mu[idx]), acc);
  }
  atomicAdd(&base[j], acc);
}

// WsG[t][j] = (mu+sg*ep)[DIN+t][DIN+j]
__global__ void ws_kernel(const float* __restrict__ mu, const float* __restrict__ sg,
                          const float* __restrict__ ep, float* __restrict__ WsG)
{
  const int t = blockIdx.x;
  const int j = threadIdx.x;
  if (j >= HOUT) return;
  const size_t idx = (size_t)(DIN + t) * NNODE + DIN + j;
  WsG[t * HOUT + j] = fmaf(sg[idx], ep[idx], mu[idx]);
}

// ---------------------------------------------------------------------------
// scan2 (verified R6): latency-minimal sequential NEAT scan. 1 wave.
// ---------------------------------------------------------------------------
__global__ __launch_bounds__(64, 1)
void scan2(const float* __restrict__ WsG, const float* __restrict__ base,
           const float* __restrict__ bmu, const float* __restrict__ bsg,
           const float* __restrict__ epb, float* __restrict__ out)
{
  __shared__ __align__(16) float tile[32 * HOUT + 128];
  const int l = threadIdx.x;

  float a0, a1, a2, a3, a4;
  {
    int j = l;       a0 = base[j] + bmu[j] + bsg[j] * epb[j];
    j = l + 64;      a1 = base[j] + bmu[j] + bsg[j] * epb[j];
    j = l + 128;     a2 = base[j] + bmu[j] + bsg[j] * epb[j];
    j = l + 192;     a3 = base[j] + bmu[j] + bsg[j] * epb[j];
    j = l + 256;     a4 = (j < HOUT) ? (base[j] + bmu[j] + bsg[j] * epb[j]) : 0.f;
  }

  float4 stg[33];
  auto LOADT = [&](int tb) {
    const int nfl = ((tb == 8) ? 4 : 32) * HOUT;
    const float* src = WsG + tb * 32 * HOUT;
#pragma unroll
    for (int c = 0; c < 33; ++c) {
      const int o = c * 256 + l * 4;
      if (o < nfl) stg[c] = *(const float4*)(src + o);
    }
  };
  auto WRITET = [&](int tb) {
    const int nfl = ((tb == 8) ? 4 : 32) * HOUT;
#pragma unroll
    for (int c = 0; c < 33; ++c) {
      const int o = c * 256 + l * 4;
      if (o < nfl) *(float4*)&tile[o] = stg[c];
    }
  };

  float w0, w1, w2, w3, w4;
  auto PRER = [&](int trow) {
    const float* tr = tile + trow * HOUT;
    w0 = tr[l]; w1 = tr[l + 64]; w2 = tr[l + 128]; w3 = tr[l + 192]; w4 = tr[l + 256];
  };

  auto inner = [&](auto Bc, int tb, int nrows) {
    constexpr int B = Bc.value;
    for (int tt = 0; tt < nrows; ++tt) {
      const int t = tb * 32 + tt;
      float pre;
      if constexpr (B == 0) pre = readlane_f(a0, t & 63);
      else if constexpr (B == 1) pre = readlane_f(a1, t & 63);
      else if constexpr (B == 2) pre = readlane_f(a2, t & 63);
      else if constexpr (B == 3) pre = readlane_f(a3, t & 63);
      else pre = readlane_f(a4, t & 63);
      const float pc = fminf(fmaxf(pre, -12.f), 12.f);
      const float e = __expf(2.f * pc);
      const float vt = 1.f - 2.f / (e + 1.f);
      if (t >= 256 && l == 0) out[t - 256] = vt;
      if (l > t)            a0 = fmaf(vt, w0, a0);
      if (l + 64 > t)       a1 = fmaf(vt, w1, a1);
      if (l + 128 > t)      a2 = fmaf(vt, w2, a2);
      if (l + 192 > t)      a3 = fmaf(vt, w3, a3);
      if (l + 256 > t && l + 256 < HOUT) a4 = fmaf(vt, w4, a4);
      if (tt + 1 < nrows) PRER(tt + 1);
    }
  };

  LOADT(0); WRITET(0); PRER(0);

#define TILE_STEP(tb, B, nr)                                    \
  { if ((tb) < 8) LOADT((tb) + 1);                              \
    inner(std::integral_constant<int, B>{}, (tb), (nr));        \
    if ((tb) < 8) { WRITET((tb) + 1); PRER(0); } }

  TILE_STEP(0, 0, 32)
  TILE_STEP(1, 0, 32)
  TILE_STEP(2, 1, 32)
  TILE_STEP(3, 1, 32)
  TILE_STEP(4, 2, 32)
  TILE_STEP(5, 2, 32)
  TILE_STEP(6, 3, 32)
  TILE_STEP(7, 3, 32)
  TILE_STEP(8, 4, 4)
#undef TILE_STEP
}

// ---------------------------------------------------------------------------
extern "C" void kernel_launch(void* const* d_in, const int* in_sizes, int n_in,
                              void* d_out, int out_size, void* d_ws, size_t ws_size,
                              hipStream_t stream)
{
  const float* X   = (const float*)d_in[0];
  const float* Wq  = (const float*)d_in[1];
  const float* bq  = (const float*)d_in[2];
  const float* Wk  = (const float*)d_in[3];
  const float* bk  = (const float*)d_in[4];
  const float* Wv  = (const float*)d_in[5];
  const float* bv  = (const float*)d_in[6];
  const float* wmu = (const float*)d_in[7];
  const float* wsg = (const float*)d_in[8];
  const float* bmu = (const float*)d_in[9];
  const float* bsg = (const float*)d_in[10];
  const float* epw = (const float*)d_in[11];
  const float* epb = (const float*)d_in[12];

  char* p = (char*)d_ws;
  auto alloc = [&](size_t bytes) -> char* {
    char* r = p;
    p += (bytes + 255) & ~(size_t)255;
    return r;
  };
  char* XbT2 = alloc((size_t)64 * 65536);                                  // 4MB
  unsigned short* PQK = (unsigned short*)alloc((size_t)8 * 256 * KP * 2);  // 32MB
  unsigned short* Qbf = (unsigned short*)alloc((size_t)256 * KP * 2);      // 4MB
  unsigned short* Kbf = (unsigned short*)alloc((size_t)256 * KP * 2);      // 4MB
  float* LP   = (float*)alloc((size_t)16 * 65536 * 4);                     // 4MB
  float* abar = (float*)alloc(256 * 4);
  float* y    = (float*)alloc(7686 * 4);
  float* ctx  = (float*)alloc(7686 * 4);
  float* base = (float*)alloc(HOUT * 4);
  float* WsG  = (float*)alloc((size_t)HOUT * HOUT * 4 + 1024);

  prep_x2<<<dim3(256), dim3(256), 0, stream>>>(X, XbT2);
  (void)hipMemsetAsync(abar, 0, 256 * 4, stream);
  (void)hipMemsetAsync(base, 0, HOUT * 4, stream);

  gemm_qk7<<<dim3(241, 2, 4), dim3(512), 0, stream>>>(XbT2, Wq, Wk, PQK);
  reduce_qk4<<<dim3(64, 2), dim3(128), 0, stream>>>(PQK, bq, bk, Qbf, Kbf);
  gemm_logits<<<dim3(4, 1, 16), dim3(512), 0, stream>>>(Qbf, Kbf, LP);
  softmax_fused<<<dim3(256), dim3(256), 0, stream>>>(LP, abar);
  y_kernel<<<dim3(31), dim3(256), 0, stream>>>(X, abar, y);
  ctx_mv<<<dim3(961), dim3(512), 0, stream>>>(Wv, y, bv, ctx);
  base_kernel<<<dim3(256), dim3(320), 0, stream>>>(wmu, wsg, epw, ctx, base);
  ws_kernel<<<dim3(260), dim3(320), 0, stream>>>(wmu, wsg, epw, WsG);
  scan2<<<dim3(1), dim3(64), 0, stream>>>(WsG, base, bmu, bsg, epb, (float*)d_out);
}

// Round 14
// 378.708 us; speedup vs baseline: 1.3881x; 1.0615x over previous
//
#include <hip/hip_runtime.h>
#include <hip/hip_bf16.h>
#include <type_traits>

#define DIN   7686
#define NNODE 7946
#define HOUT  260
#define KP    8192   // padded k (64 kc-blocks of 128)
#define BROW  1036   // panel row stride in shorts (1024 + 12 pad -> 2-way banks)

typedef __attribute__((ext_vector_type(8))) short bf16x8;
typedef __attribute__((ext_vector_type(4))) float f32x4;
typedef __attribute__((ext_vector_type(2))) float f32x2;

__device__ __forceinline__ unsigned int f2b(float f) {
  union { float f; unsigned int u; } v; v.f = f;
  return (v.u + 0x7FFFu + ((v.u >> 16) & 1u)) >> 16;  // RNE float->bf16
}
__device__ __forceinline__ unsigned int pack2(float lo, float hi) {
  unsigned int r;
  asm("v_cvt_pk_bf16_f32 %0, %1, %2" : "=v"(r) : "v"(lo), "v"(hi));
  return r;
}
__device__ __forceinline__ float b2f(unsigned short h) {
  union { unsigned int u; float f; } v; v.u = ((unsigned int)h) << 16; return v.f;
}
__device__ __forceinline__ float readlane_f(float v, int lane) {
  return __uint_as_float(__builtin_amdgcn_readlane(__float_as_uint(v), lane));
}

// ---------------------------------------------------------------------------
// prep_x2 (verified R7-R13): fp32 X -> bf16 FRAGMENT-MAJOR for direct MFMA
// A-loads: block(kc 0..63, i16 0..15, ks 0..3) = 1KB at ((kc*16+i16)*4+ks)*1024
// lane l: m = i16*16 + (l&15), k = kc*128 + ks*32 + (l>>4)*8 .. +8. Pads zero.
// ---------------------------------------------------------------------------
__global__ void prep_x2(const float* __restrict__ X, char* __restrict__ XbT2)
{
  const int m = blockIdx.x, t = threadIdx.x;
  const float* row = X + (size_t)m * DIN;
  const int i16 = m >> 4;
#pragma unroll
  for (int c2 = 0; c2 < 4; ++c2) {
    const int k8 = (c2 * 256 + t) * 8;
    float f[8];
    if (k8 + 8 <= DIN) {
#pragma unroll
      for (int h = 0; h < 4; ++h) {
        float2 v = *(const float2*)(row + k8 + h * 2);
        f[h * 2] = v.x; f[h * 2 + 1] = v.y;
      }
    } else {
#pragma unroll
      for (int h = 0; h < 8; ++h) f[h] = (k8 + h < DIN) ? row[k8 + h] : 0.f;
    }
    uint4 o;
    o.x = pack2(f[0], f[1]); o.y = pack2(f[2], f[3]);
    o.z = pack2(f[4], f[5]); o.w = pack2(f[6], f[7]);
    const int kc = k8 >> 7, kk = k8 & 127, ks = kk >> 5, hq = (kk & 31) >> 3;
    const int lane = (m & 15) + (hq << 4);
    char* dst = XbT2 + ((((size_t)kc * 16 + i16) * 4 + ks) << 10) + lane * 16;
    *(uint4*)dst = o;
  }
}

// ---------------------------------------------------------------------------
// gemm_qk8: phase-separated panel GEMM with MAX IN-FLIGHT staging.
// WG = 32 W-rows x 2 k-eighths (z = zg, zg+4), 512 thr = 8 waves.
// Phase 1: ALL 16 f32x4 nontemporal loads (16 KB/wave) issued BEFORE any
//   pack/LDS-write -> 256 KB in flight per CU -> HBM-bound (Little's law).
// Phase 2: 32 MFMA steps, no barriers, A-ring depth 3 from L2-resident XbT2.
// LDS 64.8 KB -> 2 WGs/CU. grid (241, 2, 4) = 1928 WGs.
// ---------------------------------------------------------------------------
__global__ __launch_bounds__(512, 4)
void gemm_qk8(const char* __restrict__ XbT2,
              const float* __restrict__ Wq, const float* __restrict__ Wk,
              unsigned short* __restrict__ PQK)
{
  const int nt = blockIdx.x, mat = blockIdx.y, zg = blockIdx.z;
  const float* W = mat ? Wk : Wq;
  const int n0 = nt * 32;
  const int tid = threadIdx.x, l = tid & 63, wv = tid >> 6;
  const int lm = l & 15, hq = l >> 4;

  __shared__ __align__(16) unsigned short Bp[32 * BROW];  // 66,304 B

  const long long DD = (long long)DIN * DIN;

  f32x4 acc[2][2] = {};
  bf16x8 A0[2], A1[2], A2[2];
  f32x4 F[16];

  long long rb[4];
#pragma unroll
  for (int r = 0; r < 4; ++r) {
    int grow = n0 + wv * 4 + r; if (grow > DIN - 1) grow = DIN - 1;
    rb[r] = (long long)grow * DIN;
  }

#define LOADW(z_) {                                                       \
    const int k0_ = (z_) * 1024;                                          \
    _Pragma("unroll")                                                     \
    for (int r_ = 0; r_ < 4; ++r_)                                        \
      _Pragma("unroll")                                                   \
      for (int c_ = 0; c_ < 4; ++c_) {                                    \
        long long gi_ = rb[r_] + k0_ + c_ * 256 + l * 4;                  \
        if (gi_ > DD - 4) gi_ = DD - 4;  /* tail-safe; A pads zero */     \
        F[r_ * 4 + c_] = __builtin_nontemporal_load((const f32x4*)(W + gi_)); \
      } }

#define WRITEW() {                                                        \
    _Pragma("unroll")                                                     \
    for (int r_ = 0; r_ < 4; ++r_) {                                      \
      unsigned short* dr_ = &Bp[(wv * 4 + r_) * BROW];                    \
      _Pragma("unroll")                                                   \
      for (int c_ = 0; c_ < 4; ++c_) {                                    \
        f32x4 v_ = F[r_ * 4 + c_];                                        \
        uint2 o_; o_.x = pack2(v_[0], v_[1]); o_.y = pack2(v_[2], v_[3]); \
        *(uint2*)(dr_ + c_ * 256 + l * 4) = o_;                           \
      } } }

#define LA(dst, z_, s_) {                                                 \
    const int kc_ = (z_) * 8 + ((s_) >> 2), ks_ = (s_) & 3;               \
    const char* b_ = XbT2 +                                               \
        ((((size_t)kc_ * 16 + 2 * wv) * 4 + ks_) << 10) + l * 16;         \
    dst[0] = *(const bf16x8*)b_;                                          \
    dst[1] = *(const bf16x8*)(b_ + 4096); }

#define STEP(Ar, s_) {                                                    \
    bf16x8 b0_ = *(const bf16x8*)&Bp[lm * BROW + (s_) * 32 + hq * 8];     \
    bf16x8 b1_ = *(const bf16x8*)&Bp[(16 + lm) * BROW + (s_) * 32 + hq * 8]; \
    acc[0][0] = __builtin_amdgcn_mfma_f32_16x16x32_bf16(Ar[0], b0_, acc[0][0], 0, 0, 0); \
    acc[0][1] = __builtin_amdgcn_mfma_f32_16x16x32_bf16(Ar[0], b1_, acc[0][1], 0, 0, 0); \
    acc[1][0] = __builtin_amdgcn_mfma_f32_16x16x32_bf16(Ar[1], b0_, acc[1][0], 0, 0, 0); \
    acc[1][1] = __builtin_amdgcn_mfma_f32_16x16x32_bf16(Ar[1], b1_, acc[1][1], 0, 0, 0); }

#pragma unroll 1
  for (int h = 0; h < 2; ++h) {
    const int z = zg + h * 4;

    if (h) __syncthreads();   // all waves done reading Bp before re-stage

    LOADW(z)                  // 16 loads in flight before any consumer
    WRITEW()                  // progressive counted vmcnt by reg deps
    __syncthreads();

    // phase 2: A-ring depth 3, no barriers; VM queue = A-loads only
    LA(A0, z, 0) LA(A1, z, 1) LA(A2, z, 2)
#pragma unroll 1
    for (int su = 0; su < 30; su += 3) {
      STEP(A0, su + 0)
      if (su + 3 < 32) LA(A0, z, su + 3)
      STEP(A1, su + 1)
      if (su + 4 < 32) LA(A1, z, su + 4)
      STEP(A2, su + 2)
      if (su + 5 < 32) LA(A2, z, su + 5)
    }
    STEP(A0, 30)
    STEP(A1, 31)
  }
#undef LOADW
#undef WRITEW
#undef LA
#undef STEP

  // epilogue: bf16 partial for (mat, zg)
  unsigned short* Cp = PQK + (size_t)(mat * 4 + zg) * 256 * KP;
#pragma unroll
  for (int i = 0; i < 2; ++i) {
    const int r0 = (2 * wv + i) * 16 + hq * 4;
#pragma unroll
    for (int j = 0; j < 2; ++j) {
      const int col = n0 + j * 16 + lm;
#pragma unroll
      for (int q = 0; q < 4; ++q)
        Cp[(size_t)(r0 + q) * KP + col] = (unsigned short)f2b(acc[i][j][q]);
    }
  }
}

// ---------------------------------------------------------------------------
// reduce_qk4 (verified): sum 4 bf16 partials + bias -> Qbf/Kbf, pads zero
// ---------------------------------------------------------------------------
__global__ void reduce_qk4(const unsigned short* __restrict__ PQK,
                           const float* __restrict__ bq, const float* __restrict__ bk,
                           unsigned short* __restrict__ Qbf, unsigned short* __restrict__ Kbf)
{
  const int mat = blockIdx.y;
  const int c = blockIdx.x * 128 + threadIdx.x;
  const float* bias = mat ? bk : bq;
  const bool valid = c < DIN;
  const float bb = valid ? bias[c] : 0.f;
  const unsigned short* P0 = PQK + ((size_t)(mat * 4 + 0) * 256) * KP + c;
  const unsigned short* P1 = PQK + ((size_t)(mat * 4 + 1) * 256) * KP + c;
  const unsigned short* P2 = PQK + ((size_t)(mat * 4 + 2) * 256) * KP + c;
  const unsigned short* P3 = PQK + ((size_t)(mat * 4 + 3) * 256) * KP + c;
  unsigned short* O = (mat ? Kbf : Qbf) + c;
#pragma unroll 4
  for (int r = 0; r < 256; ++r) {
    float v = b2f(P0[(size_t)r * KP]) + b2f(P1[(size_t)r * KP]) +
              b2f(P2[(size_t)r * KP]) + b2f(P3[(size_t)r * KP]) + bb;
    if (!valid) v = 0.f;
    O[(size_t)r * KP] = (unsigned short)f2b(v);
  }
}

// ---------------------------------------------------------------------------
// logits partials (verified): LP[z][m][n] over 512-k chunks, grid (4,1,16)
// ---------------------------------------------------------------------------
__global__ __launch_bounds__(512)
void gemm_logits(const unsigned short* __restrict__ Qbf,
                 const unsigned short* __restrict__ Kbf, float* __restrict__ LP)
{
  const int qr = blockIdx.x & 1, qc = blockIdx.x >> 1, z = blockIdx.z;
  const int tid = threadIdx.x, lane = tid & 63, wv = tid >> 6;
  const int lm = lane & 15, lq = (lane >> 4) * 8;
  const int rowBase = qr * 128 + (wv & 3) * 32;
  const int colBase = qc * 128 + (wv >> 2) * 64;
  const int k0 = z * 512;
  f32x4 acc[2][4] = {};
#pragma unroll 4
  for (int ks = 0; ks < 16; ++ks) {
    bf16x8 a[2], b[4];
#pragma unroll
    for (int i = 0; i < 2; ++i)
      a[i] = *(const bf16x8*)(Qbf + (size_t)(rowBase + i * 16 + lm) * KP + k0 + ks * 32 + lq);
#pragma unroll
    for (int j = 0; j < 4; ++j)
      b[j] = *(const bf16x8*)(Kbf + (size_t)(colBase + j * 16 + lm) * KP + k0 + ks * 32 + lq);
#pragma unroll
    for (int i = 0; i < 2; ++i)
#pragma unroll
      for (int j = 0; j < 4; ++j)
        acc[i][j] = __builtin_amdgcn_mfma_f32_16x16x32_bf16(a[i], b[j], acc[i][j], 0, 0, 0);
  }
  float* out = LP + (size_t)z * 65536;
#pragma unroll
  for (int i = 0; i < 2; ++i) {
    const int r0 = rowBase + i * 16 + (lane >> 4) * 4;
#pragma unroll
    for (int j = 0; j < 4; ++j) {
      const int col = colBase + j * 16 + lm;
#pragma unroll
      for (int q = 0; q < 4; ++q)
        out[(size_t)(r0 + q) * 256 + col] = acc[i][j][q];
    }
  }
}

// ---------------------------------------------------------------------------
// fused: sum 16 logit partials -> row softmax -> atomicAdd into abar (w/ 1/256)
// ---------------------------------------------------------------------------
__global__ void softmax_fused(const float* __restrict__ LP, float* __restrict__ abar)
{
  __shared__ float red[8];
  const int m = blockIdx.x, t = threadIdx.x;
  float v = 0.f;
#pragma unroll
  for (int zz = 0; zz < 16; ++zz) v += LP[(size_t)zz * 65536 + m * 256 + t];
  const float scale = 1.0f / sqrtf((float)DIN);
  float mx = v;
#pragma unroll
  for (int o = 32; o >= 1; o >>= 1) mx = fmaxf(mx, __shfl_xor(mx, o, 64));
  if ((t & 63) == 0) red[t >> 6] = mx;
  __syncthreads();
  mx = fmaxf(fmaxf(red[0], red[1]), fmaxf(red[2], red[3]));
  float e = __expf((v - mx) * scale);
  float s = e;
#pragma unroll
  for (int o = 32; o >= 1; o >>= 1) s += __shfl_xor(s, o, 64);
  if ((t & 63) == 0) red[4 + (t >> 6)] = s;
  __syncthreads();
  s = red[4] + red[5] + red[6] + red[7];
  atomicAdd(&abar[t], e * (1.0f / 256.0f) / s);
}

// y[c] = sum_m abar[m] * X[m][c]
__global__ void y_kernel(const float* __restrict__ X, const float* __restrict__ abar,
                         float* __restrict__ y)
{
  __shared__ float ab[256];
  ab[threadIdx.x] = abar[threadIdx.x];
  __syncthreads();
  const int c = blockIdx.x * 256 + threadIdx.x;
  if (c >= DIN) return;
  float s = 0.f;
#pragma unroll 8
  for (int m = 0; m < 256; ++m) s += ab[m] * X[(size_t)m * DIN + c];
  y[c] = s;
}

// ctx[d] = Wv[d,:]·y + bv[d] — one row per wave; 30 branchless f32x4 iters
// (1 KB lane-contiguous per instr, ~5 KB in flight via unroll) + 6-float tail
__global__ __launch_bounds__(512)
void ctx_mv(const float* __restrict__ Wv, const float* __restrict__ y,
            const float* __restrict__ bv, float* __restrict__ ctx)
{
  const int wv = threadIdx.x >> 6, l = threadIdx.x & 63;
  const int row = blockIdx.x * 8 + wv;
  if (row >= DIN) return;
  const float* wr_ = Wv + (size_t)row * DIN;
  float s = 0.f;
#pragma unroll 5
  for (int it = 0; it < 30; ++it) {
    const int k = it * 256 + l * 4;
    f32x4 w4 = __builtin_nontemporal_load((const f32x4*)(wr_ + k));
    float4 y4 = *(const float4*)(y + k);
    s = fmaf(w4[0], y4.x, s);
    s = fmaf(w4[1], y4.y, s);
    s = fmaf(w4[2], y4.z, s);
    s = fmaf(w4[3], y4.w, s);
  }
  if (l < 6) s += wr_[7680 + l] * y[7680 + l];
#pragma unroll
  for (int o = 32; o >= 1; o >>= 1) s += __shfl_xor(s, o, 64);
  if (l == 0) ctx[row] = s + bv[row];
}

// base[j] += sum_{i in chunk} ctx[i] * (mu+sg*ep)[i][DIN+j]
__global__ void base_kernel(const float* __restrict__ mu, const float* __restrict__ sg,
                            const float* __restrict__ ep, const float* __restrict__ ctx,
                            float* __restrict__ base)
{
  const int j = threadIdx.x;
  if (j >= HOUT) return;
  const int i0 = blockIdx.x * 31;
  const int i1 = min(i0 + 31, DIN);
  float acc = 0.f;
#pragma unroll 4
  for (int i = i0; i < i1; ++i) {
    const size_t idx = (size_t)i * NNODE + DIN + j;
    acc = fmaf(ctx[i], fmaf(sg[idx], ep[idx], mu[idx]), acc);
  }
  atomicAdd(&base[j], acc);
}

// WsG[t][j] = (mu+sg*ep)[DIN+t][DIN+j]
__global__ void ws_kernel(const float* __restrict__ mu, const float* __restrict__ sg,
                          const float* __restrict__ ep, float* __restrict__ WsG)
{
  const int t = blockIdx.x;
  const int j = threadIdx.x;
  if (j >= HOUT) return;
  const size_t idx = (size_t)(DIN + t) * NNODE + DIN + j;
  WsG[t * HOUT + j] = fmaf(sg[idx], ep[idx], mu[idx]);
}

// ---------------------------------------------------------------------------
// scan2 (verified R6): latency-minimal sequential NEAT scan. 1 wave.
// ---------------------------------------------------------------------------
__global__ __launch_bounds__(64, 1)
void scan2(const float* __restrict__ WsG, const float* __restrict__ base,
           const float* __restrict__ bmu, const float* __restrict__ bsg,
           const float* __restrict__ epb, float* __restrict__ out)
{
  __shared__ __align__(16) float tile[32 * HOUT + 128];
  const int l = threadIdx.x;

  float a0, a1, a2, a3, a4;
  {
    int j = l;       a0 = base[j] + bmu[j] + bsg[j] * epb[j];
    j = l + 64;      a1 = base[j] + bmu[j] + bsg[j] * epb[j];
    j = l + 128;     a2 = base[j] + bmu[j] + bsg[j] * epb[j];
    j = l + 192;     a3 = base[j] + bmu[j] + bsg[j] * epb[j];
    j = l + 256;     a4 = (j < HOUT) ? (base[j] + bmu[j] + bsg[j] * epb[j]) : 0.f;
  }

  float4 stg[33];
  auto LOADT = [&](int tb) {
    const int nfl = ((tb == 8) ? 4 : 32) * HOUT;
    const float* src = WsG + tb * 32 * HOUT;
#pragma unroll
    for (int c = 0; c < 33; ++c) {
      const int o = c * 256 + l * 4;
      if (o < nfl) stg[c] = *(const float4*)(src + o);
    }
  };
  auto WRITET = [&](int tb) {
    const int nfl = ((tb == 8) ? 4 : 32) * HOUT;
#pragma unroll
    for (int c = 0; c < 33; ++c) {
      const int o = c * 256 + l * 4;
      if (o < nfl) *(float4*)&tile[o] = stg[c];
    }
  };

  float w0, w1, w2, w3, w4;
  auto PRER = [&](int trow) {
    const float* tr = tile + trow * HOUT;
    w0 = tr[l]; w1 = tr[l + 64]; w2 = tr[l + 128]; w3 = tr[l + 192]; w4 = tr[l + 256];
  };

  auto inner = [&](auto Bc, int tb, int nrows) {
    constexpr int B = Bc.value;
    for (int tt = 0; tt < nrows; ++tt) {
      const int t = tb * 32 + tt;
      float pre;
      if constexpr (B == 0) pre = readlane_f(a0, t & 63);
      else if constexpr (B == 1) pre = readlane_f(a1, t & 63);
      else if constexpr (B == 2) pre = readlane_f(a2, t & 63);
      else if constexpr (B == 3) pre = readlane_f(a3, t & 63);
      else pre = readlane_f(a4, t & 63);
      const float pc = fminf(fmaxf(pre, -12.f), 12.f);
      const float e = __expf(2.f * pc);
      const float vt = 1.f - 2.f / (e + 1.f);
      if (t >= 256 && l == 0) out[t - 256] = vt;
      if (l > t)            a0 = fmaf(vt, w0, a0);
      if (l + 64 > t)       a1 = fmaf(vt, w1, a1);
      if (l + 128 > t)      a2 = fmaf(vt, w2, a2);
      if (l + 192 > t)      a3 = fmaf(vt, w3, a3);
      if (l + 256 > t && l + 256 < HOUT) a4 = fmaf(vt, w4, a4);
      if (tt + 1 < nrows) PRER(tt + 1);
    }
  };

  LOADT(0); WRITET(0); PRER(0);

#define TILE_STEP(tb, B, nr)                                    \
  { if ((tb) < 8) LOADT((tb) + 1);                              \
    inner(std::integral_constant<int, B>{}, (tb), (nr));        \
    if ((tb) < 8) { WRITET((tb) + 1); PRER(0); } }

  TILE_STEP(0, 0, 32)
  TILE_STEP(1, 0, 32)
  TILE_STEP(2, 1, 32)
  TILE_STEP(3, 1, 32)
  TILE_STEP(4, 2, 32)
  TILE_STEP(5, 2, 32)
  TILE_STEP(6, 3, 32)
  TILE_STEP(7, 3, 32)
  TILE_STEP(8, 4, 4)
#undef TILE_STEP
}

// ---------------------------------------------------------------------------
extern "C" void kernel_launch(void* const* d_in, const int* in_sizes, int n_in,
                              void* d_out, int out_size, void* d_ws, size_t ws_size,
                              hipStream_t stream)
{
  const float* X   = (const float*)d_in[0];
  const float* Wq  = (const float*)d_in[1];
  const float* bq  = (const float*)d_in[2];
  const float* Wk  = (const float*)d_in[3];
  const float* bk  = (const float*)d_in[4];
  const float* Wv  = (const float*)d_in[5];
  const float* bv  = (const float*)d_in[6];
  const float* wmu = (const float*)d_in[7];
  const float* wsg = (const float*)d_in[8];
  const float* bmu = (const float*)d_in[9];
  const float* bsg = (const float*)d_in[10];
  const float* epw = (const float*)d_in[11];
  const float* epb = (const float*)d_in[12];

  char* p = (char*)d_ws;
  auto alloc = [&](size_t bytes) -> char* {
    char* r = p;
    p += (bytes + 255) & ~(size_t)255;
    return r;
  };
  char* XbT2 = alloc((size_t)64 * 65536);                                  // 4MB
  unsigned short* PQK = (unsigned short*)alloc((size_t)8 * 256 * KP * 2);  // 32MB
  unsigned short* Qbf = (unsigned short*)alloc((size_t)256 * KP * 2);      // 4MB
  unsigned short* Kbf = (unsigned short*)alloc((size_t)256 * KP * 2);      // 4MB
  float* LP   = (float*)alloc((size_t)16 * 65536 * 4);                     // 4MB
  float* abar = (float*)alloc(256 * 4);
  float* y    = (float*)alloc(7686 * 4);
  float* ctx  = (float*)alloc(7686 * 4);
  float* base = (float*)alloc(HOUT * 4);
  float* WsG  = (float*)alloc((size_t)HOUT * HOUT * 4 + 1024);

  prep_x2<<<dim3(256), dim3(256), 0, stream>>>(X, XbT2);
  (void)hipMemsetAsync(abar, 0, 256 * 4, stream);
  (void)hipMemsetAsync(base, 0, HOUT * 4, stream);

  gemm_qk8<<<dim3(241, 2, 4), dim3(512), 0, stream>>>(XbT2, Wq, Wk, PQK);
  reduce_qk4<<<dim3(64, 2), dim3(128), 0, stream>>>(PQK, bq, bk, Qbf, Kbf);
  gemm_logits<<<dim3(4, 1, 16), dim3(512), 0, stream>>>(Qbf, Kbf, LP);
  softmax_fused<<<dim3(256), dim3(256), 0, stream>>>(LP, abar);
  y_kernel<<<dim3(31), dim3(256), 0, stream>>>(X, abar, y);
  ctx_mv<<<dim3(961), dim3(512), 0, stream>>>(Wv, y, bv, ctx);
  base_kernel<<<dim3(256), dim3(320), 0, stream>>>(wmu, wsg, epw, ctx, base);
  ws_kernel<<<dim3(260), dim3(320), 0, stream>>>(wmu, wsg, epw, WsG);
  scan2<<<dim3(1), dim3(64), 0, stream>>>(WsG, base, bmu, bsg, epb, (float*)d_out);
}

// Round 15
// 350.127 us; speedup vs baseline: 1.5014x; 1.0816x over previous
//
#include <hip/hip_runtime.h>
#include <hip/hip_bf16.h>
#include <type_traits>

#define DIN   7686
#define NNODE 7946
#define HOUT  260
#define KP    8192   // padded k (64 kc-blocks of 128)
#define BROW  1036   // panel row stride in shorts (1024 + 12 pad -> 2-way banks)

typedef __attribute__((ext_vector_type(8))) short bf16x8;
typedef __attribute__((ext_vector_type(4))) float f32x4;
typedef __attribute__((ext_vector_type(2))) float f32x2;

__device__ __forceinline__ unsigned int f2b(float f) {
  union { float f; unsigned int u; } v; v.f = f;
  return (v.u + 0x7FFFu + ((v.u >> 16) & 1u)) >> 16;  // RNE float->bf16
}
__device__ __forceinline__ unsigned int pack2(float lo, float hi) {
  unsigned int r;
  asm("v_cvt_pk_bf16_f32 %0, %1, %2" : "=v"(r) : "v"(lo), "v"(hi));
  return r;
}
__device__ __forceinline__ float b2f(unsigned short h) {
  union { unsigned int u; float f; } v; v.u = ((unsigned int)h) << 16; return v.f;
}
__device__ __forceinline__ float readlane_f(float v, int lane) {
  return __uint_as_float(__builtin_amdgcn_readlane(__float_as_uint(v), lane));
}

// ---------------------------------------------------------------------------
// prep_x2 (verified R7-R14): fp32 X -> bf16 FRAGMENT-MAJOR for direct MFMA
// A-loads: block(kc 0..63, i16 0..15, ks 0..3) = 1KB at ((kc*16+i16)*4+ks)*1024
// lane l: m = i16*16 + (l&15), k = kc*128 + ks*32 + (l>>4)*8 .. +8. Pads zero.
// ---------------------------------------------------------------------------
__global__ void prep_x2(const float* __restrict__ X, char* __restrict__ XbT2)
{
  const int m = blockIdx.x, t = threadIdx.x;
  const float* row = X + (size_t)m * DIN;
  const int i16 = m >> 4;
#pragma unroll
  for (int c2 = 0; c2 < 4; ++c2) {
    const int k8 = (c2 * 256 + t) * 8;
    float f[8];
    if (k8 + 8 <= DIN) {
#pragma unroll
      for (int h = 0; h < 4; ++h) {
        float2 v = *(const float2*)(row + k8 + h * 2);
        f[h * 2] = v.x; f[h * 2 + 1] = v.y;
      }
    } else {
#pragma unroll
      for (int h = 0; h < 8; ++h) f[h] = (k8 + h < DIN) ? row[k8 + h] : 0.f;
    }
    uint4 o;
    o.x = pack2(f[0], f[1]); o.y = pack2(f[2], f[3]);
    o.z = pack2(f[4], f[5]); o.w = pack2(f[6], f[7]);
    const int kc = k8 >> 7, kk = k8 & 127, ks = kk >> 5, hq = (kk & 31) >> 3;
    const int lane = (m & 15) + (hq << 4);
    char* dst = XbT2 + ((((size_t)kc * 16 + i16) * 4 + ks) << 10) + lane * 16;
    *(uint4*)dst = o;
  }
}

// ---------------------------------------------------------------------------
// gemm_qk9: full-K phase-separated panel GEMM (R14 structure, k-split removed).
// WG = 32 W-rows x FULL K (8 chunks of 1024), 512 thr = 8 waves.
// Per chunk: batch-issue 16 f32x4 nontemporal W loads (16 KB/wave in flight)
//   -> pack -> LDS panel -> 32 barrier-free MFMA steps (A-ring depth 3 from
//   L2-resident XbT2). acc lives in registers across all 8 chunks.
// Output: Qbf/Kbf bf16 DIRECTLY (+bias, zero pad cols) — no partials,
// no reduce pass. LDS 64.8 KB -> 2 WGs/CU. grid (241, 2) = 482 WGs.
// ---------------------------------------------------------------------------
__global__ __launch_bounds__(512, 4)
void gemm_qk9(const char* __restrict__ XbT2,
              const float* __restrict__ Wq, const float* __restrict__ Wk,
              const float* __restrict__ bq, const float* __restrict__ bk,
              unsigned short* __restrict__ Qbf, unsigned short* __restrict__ Kbf)
{
  const int nt = blockIdx.x, mat = blockIdx.y;
  const float* W = mat ? Wk : Wq;
  const float* bias = mat ? bk : bq;
  unsigned short* Out = mat ? Kbf : Qbf;
  const int n0 = nt * 32;
  const int tid = threadIdx.x, l = tid & 63, wv = tid >> 6;
  const int lm = l & 15, hq = l >> 4;

  __shared__ __align__(16) unsigned short Bp[32 * BROW];  // 66,304 B

  const long long DD = (long long)DIN * DIN;

  f32x4 acc[2][2] = {};
  bf16x8 A0[2], A1[2], A2[2];
  f32x4 F[16];

  long long rb[4];
#pragma unroll
  for (int r = 0; r < 4; ++r) {
    int grow = n0 + wv * 4 + r; if (grow > DIN - 1) grow = DIN - 1;
    rb[r] = (long long)grow * DIN;
  }

#define LOADW(z_) {                                                       \
    const int k0_ = (z_) * 1024;                                          \
    _Pragma("unroll")                                                     \
    for (int r_ = 0; r_ < 4; ++r_)                                        \
      _Pragma("unroll")                                                   \
      for (int c_ = 0; c_ < 4; ++c_) {                                    \
        long long gi_ = rb[r_] + k0_ + c_ * 256 + l * 4;                  \
        if (gi_ > DD - 4) gi_ = DD - 4;  /* tail-safe; A pads zero */     \
        F[r_ * 4 + c_] = __builtin_nontemporal_load((const f32x4*)(W + gi_)); \
      } }

#define WRITEW() {                                                        \
    _Pragma("unroll")                                                     \
    for (int r_ = 0; r_ < 4; ++r_) {                                      \
      unsigned short* dr_ = &Bp[(wv * 4 + r_) * BROW];                    \
      _Pragma("unroll")                                                   \
      for (int c_ = 0; c_ < 4; ++c_) {                                    \
        f32x4 v_ = F[r_ * 4 + c_];                                        \
        uint2 o_; o_.x = pack2(v_[0], v_[1]); o_.y = pack2(v_[2], v_[3]); \
        *(uint2*)(dr_ + c_ * 256 + l * 4) = o_;                           \
      } } }

#define LA(dst, z_, s_) {                                                 \
    const int kc_ = (z_) * 8 + ((s_) >> 2), ks_ = (s_) & 3;               \
    const char* b_ = XbT2 +                                               \
        ((((size_t)kc_ * 16 + 2 * wv) * 4 + ks_) << 10) + l * 16;         \
    dst[0] = *(const bf16x8*)b_;                                          \
    dst[1] = *(const bf16x8*)(b_ + 4096); }

#define STEP(Ar, s_) {                                                    \
    bf16x8 b0_ = *(const bf16x8*)&Bp[lm * BROW + (s_) * 32 + hq * 8];     \
    bf16x8 b1_ = *(const bf16x8*)&Bp[(16 + lm) * BROW + (s_) * 32 + hq * 8]; \
    acc[0][0] = __builtin_amdgcn_mfma_f32_16x16x32_bf16(Ar[0], b0_, acc[0][0], 0, 0, 0); \
    acc[0][1] = __builtin_amdgcn_mfma_f32_16x16x32_bf16(Ar[0], b1_, acc[0][1], 0, 0, 0); \
    acc[1][0] = __builtin_amdgcn_mfma_f32_16x16x32_bf16(Ar[1], b0_, acc[1][0], 0, 0, 0); \
    acc[1][1] = __builtin_amdgcn_mfma_f32_16x16x32_bf16(Ar[1], b1_, acc[1][1], 0, 0, 0); }

#pragma unroll 1
  for (int z = 0; z < 8; ++z) {
    if (z) __syncthreads();   // all waves done reading Bp before re-stage

    LOADW(z)                  // 16 loads (16 KB/wave) in flight before use
    WRITEW()                  // progressive counted vmcnt by reg deps
    __syncthreads();

    // phase 2: A-ring depth 3, no barriers; VM queue = A-loads only
    LA(A0, z, 0) LA(A1, z, 1) LA(A2, z, 2)
#pragma unroll 1
    for (int su = 0; su < 30; su += 3) {
      STEP(A0, su + 0)
      if (su + 3 < 32) LA(A0, z, su + 3)
      STEP(A1, su + 1)
      if (su + 4 < 32) LA(A1, z, su + 4)
      STEP(A2, su + 2)
      if (su + 5 < 32) LA(A2, z, su + 5)
    }
    STEP(A0, 30)
    STEP(A1, 31)
  }
#undef LOADW
#undef WRITEW
#undef LA
#undef STEP

  // epilogue: Out[m][col] = acc + bias (bf16); col >= DIN -> 0
#pragma unroll
  for (int i = 0; i < 2; ++i) {
    const int r0 = (2 * wv + i) * 16 + hq * 4;
#pragma unroll
    for (int j = 0; j < 2; ++j) {
      const int col = n0 + j * 16 + lm;
      const float bb = (col < DIN) ? bias[col] : 0.f;
#pragma unroll
      for (int q = 0; q < 4; ++q) {
        const float v = acc[i][j][q] + bb;
        Out[(size_t)(r0 + q) * KP + col] = (col < DIN) ? (unsigned short)f2b(v) : 0;
      }
    }
  }
}

// ---------------------------------------------------------------------------
// logits partials (verified): LP[z][m][n] over 512-k chunks, grid (4,1,16)
// ---------------------------------------------------------------------------
__global__ __launch_bounds__(512)
void gemm_logits(const unsigned short* __restrict__ Qbf,
                 const unsigned short* __restrict__ Kbf, float* __restrict__ LP)
{
  const int qr = blockIdx.x & 1, qc = blockIdx.x >> 1, z = blockIdx.z;
  const int tid = threadIdx.x, lane = tid & 63, wv = tid >> 6;
  const int lm = lane & 15, lq = (lane >> 4) * 8;
  const int rowBase = qr * 128 + (wv & 3) * 32;
  const int colBase = qc * 128 + (wv >> 2) * 64;
  const int k0 = z * 512;
  f32x4 acc[2][4] = {};
#pragma unroll 4
  for (int ks = 0; ks < 16; ++ks) {
    bf16x8 a[2], b[4];
#pragma unroll
    for (int i = 0; i < 2; ++i)
      a[i] = *(const bf16x8*)(Qbf + (size_t)(rowBase + i * 16 + lm) * KP + k0 + ks * 32 + lq);
#pragma unroll
    for (int j = 0; j < 4; ++j)
      b[j] = *(const bf16x8*)(Kbf + (size_t)(colBase + j * 16 + lm) * KP + k0 + ks * 32 + lq);
#pragma unroll
    for (int i = 0; i < 2; ++i)
#pragma unroll
      for (int j = 0; j < 4; ++j)
        acc[i][j] = __builtin_amdgcn_mfma_f32_16x16x32_bf16(a[i], b[j], acc[i][j], 0, 0, 0);
  }
  float* out = LP + (size_t)z * 65536;
#pragma unroll
  for (int i = 0; i < 2; ++i) {
    const int r0 = rowBase + i * 16 + (lane >> 4) * 4;
#pragma unroll
    for (int j = 0; j < 4; ++j) {
      const int col = colBase + j * 16 + lm;
#pragma unroll
      for (int q = 0; q < 4; ++q)
        out[(size_t)(r0 + q) * 256 + col] = acc[i][j][q];
    }
  }
}

// ---------------------------------------------------------------------------
// fused: sum 16 logit partials -> row softmax -> atomicAdd into abar (w/ 1/256)
// ---------------------------------------------------------------------------
__global__ void softmax_fused(const float* __restrict__ LP, float* __restrict__ abar)
{
  __shared__ float red[8];
  const int m = blockIdx.x, t = threadIdx.x;
  float v = 0.f;
#pragma unroll
  for (int zz = 0; zz < 16; ++zz) v += LP[(size_t)zz * 65536 + m * 256 + t];
  const float scale = 1.0f / sqrtf((float)DIN);
  float mx = v;
#pragma unroll
  for (int o = 32; o >= 1; o >>= 1) mx = fmaxf(mx, __shfl_xor(mx, o, 64));
  if ((t & 63) == 0) red[t >> 6] = mx;
  __syncthreads();
  mx = fmaxf(fmaxf(red[0], red[1]), fmaxf(red[2], red[3]));
  float e = __expf((v - mx) * scale);
  float s = e;
#pragma unroll
  for (int o = 32; o >= 1; o >>= 1) s += __shfl_xor(s, o, 64);
  if ((t & 63) == 0) red[4 + (t >> 6)] = s;
  __syncthreads();
  s = red[4] + red[5] + red[6] + red[7];
  atomicAdd(&abar[t], e * (1.0f / 256.0f) / s);
}

// y[c] = sum_m abar[m] * X[m][c]
__global__ void y_kernel(const float* __restrict__ X, const float* __restrict__ abar,
                         float* __restrict__ y)
{
  __shared__ float ab[256];
  ab[threadIdx.x] = abar[threadIdx.x];
  __syncthreads();
  const int c = blockIdx.x * 256 + threadIdx.x;
  if (c >= DIN) return;
  float s = 0.f;
#pragma unroll 8
  for (int m = 0; m < 256; ++m) s += ab[m] * X[(size_t)m * DIN + c];
  y[c] = s;
}

// ctx[d] = Wv[d,:]·y + bv[d] — one row per wave; 30 branchless f32x4 iters
__global__ __launch_bounds__(512)
void ctx_mv(const float* __restrict__ Wv, const float* __restrict__ y,
            const float* __restrict__ bv, float* __restrict__ ctx)
{
  const int wv = threadIdx.x >> 6, l = threadIdx.x & 63;
  const int row = blockIdx.x * 8 + wv;
  if (row >= DIN) return;
  const float* wr_ = Wv + (size_t)row * DIN;
  float s = 0.f;
#pragma unroll 5
  for (int it = 0; it < 30; ++it) {
    const int k = it * 256 + l * 4;
    f32x4 w4 = __builtin_nontemporal_load((const f32x4*)(wr_ + k));
    float4 y4 = *(const float4*)(y + k);
    s = fmaf(w4[0], y4.x, s);
    s = fmaf(w4[1], y4.y, s);
    s = fmaf(w4[2], y4.z, s);
    s = fmaf(w4[3], y4.w, s);
  }
  if (l < 6) s += wr_[7680 + l] * y[7680 + l];
#pragma unroll
  for (int o = 32; o >= 1; o >>= 1) s += __shfl_xor(s, o, 64);
  if (l == 0) ctx[row] = s + bv[row];
}

// base[j] += sum_{i in chunk} ctx[i] * (mu+sg*ep)[i][DIN+j]
__global__ void base_kernel(const float* __restrict__ mu, const float* __restrict__ sg,
                            const float* __restrict__ ep, const float* __restrict__ ctx,
                            float* __restrict__ base)
{
  const int j = threadIdx.x;
  if (j >= HOUT) return;
  const int i0 = blockIdx.x * 31;
  const int i1 = min(i0 + 31, DIN);
  float acc = 0.f;
#pragma unroll 4
  for (int i = i0; i < i1; ++i) {
    const size_t idx = (size_t)i * NNODE + DIN + j;
    acc = fmaf(ctx[i], fmaf(sg[idx], ep[idx], mu[idx]), acc);
  }
  atomicAdd(&base[j], acc);
}

// WsG[t][j] = (mu+sg*ep)[DIN+t][DIN+j]
__global__ void ws_kernel(const float* __restrict__ mu, const float* __restrict__ sg,
                          const float* __restrict__ ep, float* __restrict__ WsG)
{
  const int t = blockIdx.x;
  const int j = threadIdx.x;
  if (j >= HOUT) return;
  const size_t idx = (size_t)(DIN + t) * NNODE + DIN + j;
  WsG[t * HOUT + j] = fmaf(sg[idx], ep[idx], mu[idx]);
}

// ---------------------------------------------------------------------------
// scan2 (verified R6): latency-minimal sequential NEAT scan. 1 wave.
// ---------------------------------------------------------------------------
__global__ __launch_bounds__(64, 1)
void scan2(const float* __restrict__ WsG, const float* __restrict__ base,
           const float* __restrict__ bmu, const float* __restrict__ bsg,
           const float* __restrict__ epb, float* __restrict__ out)
{
  __shared__ __align__(16) float tile[32 * HOUT + 128];
  const int l = threadIdx.x;

  float a0, a1, a2, a3, a4;
  {
    int j = l;       a0 = base[j] + bmu[j] + bsg[j] * epb[j];
    j = l + 64;      a1 = base[j] + bmu[j] + bsg[j] * epb[j];
    j = l + 128;     a2 = base[j] + bmu[j] + bsg[j] * epb[j];
    j = l + 192;     a3 = base[j] + bmu[j] + bsg[j] * epb[j];
    j = l + 256;     a4 = (j < HOUT) ? (base[j] + bmu[j] + bsg[j] * epb[j]) : 0.f;
  }

  float4 stg[33];
  auto LOADT = [&](int tb) {
    const int nfl = ((tb == 8) ? 4 : 32) * HOUT;
    const float* src = WsG + tb * 32 * HOUT;
#pragma unroll
    for (int c = 0; c < 33; ++c) {
      const int o = c * 256 + l * 4;
      if (o < nfl) stg[c] = *(const float4*)(src + o);
    }
  };
  auto WRITET = [&](int tb) {
    const int nfl = ((tb == 8) ? 4 : 32) * HOUT;
#pragma unroll
    for (int c = 0; c < 33; ++c) {
      const int o = c * 256 + l * 4;
      if (o < nfl) *(float4*)&tile[o] = stg[c];
    }
  };

  float w0, w1, w2, w3, w4;
  auto PRER = [&](int trow) {
    const float* tr = tile + trow * HOUT;
    w0 = tr[l]; w1 = tr[l + 64]; w2 = tr[l + 128]; w3 = tr[l + 192]; w4 = tr[l + 256];
  };

  auto inner = [&](auto Bc, int tb, int nrows) {
    constexpr int B = Bc.value;
    for (int tt = 0; tt < nrows; ++tt) {
      const int t = tb * 32 + tt;
      float pre;
      if constexpr (B == 0) pre = readlane_f(a0, t & 63);
      else if constexpr (B == 1) pre = readlane_f(a1, t & 63);
      else if constexpr (B == 2) pre = readlane_f(a2, t & 63);
      else if constexpr (B == 3) pre = readlane_f(a3, t & 63);
      else pre = readlane_f(a4, t & 63);
      const float pc = fminf(fmaxf(pre, -12.f), 12.f);
      const float e = __expf(2.f * pc);
      const float vt = 1.f - 2.f / (e + 1.f);
      if (t >= 256 && l == 0) out[t - 256] = vt;
      if (l > t)            a0 = fmaf(vt, w0, a0);
      if (l + 64 > t)       a1 = fmaf(vt, w1, a1);
      if (l + 128 > t)      a2 = fmaf(vt, w2, a2);
      if (l + 192 > t)      a3 = fmaf(vt, w3, a3);
      if (l + 256 > t && l + 256 < HOUT) a4 = fmaf(vt, w4, a4);
      if (tt + 1 < nrows) PRER(tt + 1);
    }
  };

  LOADT(0); WRITET(0); PRER(0);

#define TILE_STEP(tb, B, nr)                                    \
  { if ((tb) < 8) LOADT((tb) + 1);                              \
    inner(std::integral_constant<int, B>{}, (tb), (nr));        \
    if ((tb) < 8) { WRITET((tb) + 1); PRER(0); } }

  TILE_STEP(0, 0, 32)
  TILE_STEP(1, 0, 32)
  TILE_STEP(2, 1, 32)
  TILE_STEP(3, 1, 32)
  TILE_STEP(4, 2, 32)
  TILE_STEP(5, 2, 32)
  TILE_STEP(6, 3, 32)
  TILE_STEP(7, 3, 32)
  TILE_STEP(8, 4, 4)
#undef TILE_STEP
}

// ---------------------------------------------------------------------------
extern "C" void kernel_launch(void* const* d_in, const int* in_sizes, int n_in,
                              void* d_out, int out_size, void* d_ws, size_t ws_size,
                              hipStream_t stream)
{
  const float* X   = (const float*)d_in[0];
  const float* Wq  = (const float*)d_in[1];
  const float* bq  = (const float*)d_in[2];
  const float* Wk  = (const float*)d_in[3];
  const float* bk  = (const float*)d_in[4];
  const float* Wv  = (const float*)d_in[5];
  const float* bv  = (const float*)d_in[6];
  const float* wmu = (const float*)d_in[7];
  const float* wsg = (const float*)d_in[8];
  const float* bmu = (const float*)d_in[9];
  const float* bsg = (const float*)d_in[10];
  const float* epw = (const float*)d_in[11];
  const float* epb = (const float*)d_in[12];

  char* p = (char*)d_ws;
  auto alloc = [&](size_t bytes) -> char* {
    char* r = p;
    p += (bytes + 255) & ~(size_t)255;
    return r;
  };
  char* XbT2 = alloc((size_t)64 * 65536);                                  // 4MB
  unsigned short* Qbf = (unsigned short*)alloc((size_t)256 * KP * 2);      // 4MB
  unsigned short* Kbf = (unsigned short*)alloc((size_t)256 * KP * 2);      // 4MB
  float* LP   = (float*)alloc((size_t)16 * 65536 * 4);                     // 4MB
  float* abar = (float*)alloc(256 * 4);
  float* y    = (float*)alloc(7686 * 4);
  float* ctx  = (float*)alloc(7686 * 4);
  float* base = (float*)alloc(HOUT * 4);
  float* WsG  = (float*)alloc((size_t)HOUT * HOUT * 4 + 1024);

  prep_x2<<<dim3(256), dim3(256), 0, stream>>>(X, XbT2);
  (void)hipMemsetAsync(abar, 0, 256 * 4, stream);
  (void)hipMemsetAsync(base, 0, HOUT * 4, stream);
  (void)hipMemsetAsync(Qbf, 0, (size_t)256 * KP * 2, stream);
  (void)hipMemsetAsync(Kbf, 0, (size_t)256 * KP * 2, stream);

  gemm_qk9<<<dim3(241, 2), dim3(512), 0, stream>>>(XbT2, Wq, Wk, bq, bk, Qbf, Kbf);
  gemm_logits<<<dim3(4, 1, 16), dim3(512), 0, stream>>>(Qbf, Kbf, LP);
  softmax_fused<<<dim3(256), dim3(256), 0, stream>>>(LP, abar);
  y_kernel<<<dim3(31), dim3(256), 0, stream>>>(X, abar, y);
  ctx_mv<<<dim3(961), dim3(512), 0, stream>>>(Wv, y, bv, ctx);
  base_kernel<<<dim3(256), dim3(320), 0, stream>>>(wmu, wsg, epw, ctx, base);
  ws_kernel<<<dim3(260), dim3(320), 0, stream>>>(wmu, wsg, epw, WsG);
  scan2<<<dim3(1), dim3(64), 0, stream>>>(WsG, base, bmu, bsg, epb, (float*)d_out);
}

// Round 16
// 349.039 us; speedup vs baseline: 1.5060x; 1.0031x over previous
//
#include <hip/hip_runtime.h>
#include <hip/hip_bf16.h>
#include <type_traits>

#define DIN   7686
#define NNODE 7946
#define HOUT  260
#define KP    8192   // padded k (64 kc-blocks of 128)
#define PROW  520    // panel row stride in shorts (512 + 8 pad)

typedef __attribute__((ext_vector_type(8))) short bf16x8;
typedef __attribute__((ext_vector_type(4))) float f32x4;
typedef __attribute__((ext_vector_type(2))) float f32x2;

__device__ __forceinline__ unsigned int f2b(float f) {
  union { float f; unsigned int u; } v; v.f = f;
  return (v.u + 0x7FFFu + ((v.u >> 16) & 1u)) >> 16;  // RNE float->bf16
}
__device__ __forceinline__ unsigned int pack2(float lo, float hi) {
  unsigned int r;
  asm("v_cvt_pk_bf16_f32 %0, %1, %2" : "=v"(r) : "v"(lo), "v"(hi));
  return r;
}
__device__ __forceinline__ float b2f(unsigned short h) {
  union { unsigned int u; float f; } v; v.u = ((unsigned int)h) << 16; return v.f;
}
__device__ __forceinline__ float readlane_f(float v, int lane) {
  return __uint_as_float(__builtin_amdgcn_readlane(__float_as_uint(v), lane));
}

// ---------------------------------------------------------------------------
// prep_x2 (verified R7-R15): fp32 X -> bf16 FRAGMENT-MAJOR for direct MFMA
// A-loads: block(kc 0..63, i16 0..15, ks 0..3) = 1KB at ((kc*16+i16)*4+ks)*1024
// lane l: m = i16*16 + (l&15), k = kc*128 + ks*32 + (l>>4)*8 .. +8. Pads zero.
// ---------------------------------------------------------------------------
__global__ void prep_x2(const float* __restrict__ X, char* __restrict__ XbT2)
{
  const int m = blockIdx.x, t = threadIdx.x;
  const float* row = X + (size_t)m * DIN;
  const int i16 = m >> 4;
#pragma unroll
  for (int c2 = 0; c2 < 4; ++c2) {
    const int k8 = (c2 * 256 + t) * 8;
    float f[8];
    if (k8 + 8 <= DIN) {
#pragma unroll
      for (int h = 0; h < 4; ++h) {
        float2 v = *(const float2*)(row + k8 + h * 2);
        f[h * 2] = v.x; f[h * 2 + 1] = v.y;
      }
    } else {
#pragma unroll
      for (int h = 0; h < 8; ++h) f[h] = (k8 + h < DIN) ? row[k8 + h] : 0.f;
    }
    uint4 o;
    o.x = pack2(f[0], f[1]); o.y = pack2(f[2], f[3]);
    o.z = pack2(f[4], f[5]); o.w = pack2(f[6], f[7]);
    const int kc = k8 >> 7, kk = k8 & 127, ks = kk >> 5, hq = (kk & 31) >> 3;
    const int lane = (m & 15) + (hq << 4);
    char* dst = XbT2 + ((((size_t)kc * 16 + i16) * 4 + ks) << 10) + lane * 16;
    *(uint4*)dst = o;
  }
}

// ---------------------------------------------------------------------------
// gemm_qk10: full-K phase-separated panel GEMM, BN=64 (A-L2-traffic halved).
// WG = 64 W-rows x FULL K (16 chunks of 512), 512 thr = 8 waves.
// Per chunk: wave stages its 8 rows in 2 batches of 8 f32x4 nontemporal
//   loads (8 KB in flight) -> pack -> LDS panel [64][520] (66.6 KB).
//   Then 16 barrier-free MFMA steps: 2 A-frag m-blocks x 4 B n-blocks
//   (8 MFMA/step), A-ring depth 2 from L2-resident XbT2.
// Output: Qbf/Kbf bf16 directly (+bias, zero pads). 2 WGs/CU.
// grid (121, 2) = 242 WGs.
// ---------------------------------------------------------------------------
__global__ __launch_bounds__(512, 4)
void gemm_qk10(const char* __restrict__ XbT2,
               const float* __restrict__ Wq, const float* __restrict__ Wk,
               const float* __restrict__ bq, const float* __restrict__ bk,
               unsigned short* __restrict__ Qbf, unsigned short* __restrict__ Kbf)
{
  const int nt = blockIdx.x, mat = blockIdx.y;
  const float* W = mat ? Wk : Wq;
  const float* bias = mat ? bk : bq;
  unsigned short* Out = mat ? Kbf : Qbf;
  const int n0 = nt * 64;
  const int tid = threadIdx.x, l = tid & 63, wv = tid >> 6;
  const int lm = l & 15, hq = l >> 4;

  __shared__ __align__(16) unsigned short Bp[64 * PROW];  // 66,560 B

  const long long DD = (long long)DIN * DIN;

  f32x4 acc[2][4] = {};
  bf16x8 A0[2], A1[2];
  f32x4 F[8];

#define LOADH(z_, rh_) {                                                  \
    _Pragma("unroll")                                                     \
    for (int r_ = 0; r_ < 4; ++r_) {                                      \
      int grow_ = n0 + wv * 8 + (rh_) * 4 + r_;                           \
      if (grow_ > DIN - 1) grow_ = DIN - 1;                               \
      const long long gb_ = (long long)grow_ * DIN + (z_) * 512;          \
      _Pragma("unroll")                                                   \
      for (int c_ = 0; c_ < 2; ++c_) {                                    \
        long long gi_ = gb_ + c_ * 256 + l * 4;                           \
        if (gi_ > DD - 4) gi_ = DD - 4;  /* tail-safe; A pads zero */     \
        F[r_ * 2 + c_] = __builtin_nontemporal_load((const f32x4*)(W + gi_)); \
      } } }

#define WRITEH(rh_) {                                                     \
    _Pragma("unroll")                                                     \
    for (int r_ = 0; r_ < 4; ++r_) {                                      \
      unsigned short* dr_ = &Bp[(wv * 8 + (rh_) * 4 + r_) * PROW];        \
      _Pragma("unroll")                                                   \
      for (int c_ = 0; c_ < 2; ++c_) {                                    \
        f32x4 v_ = F[r_ * 2 + c_];                                        \
        uint2 o_; o_.x = pack2(v_[0], v_[1]); o_.y = pack2(v_[2], v_[3]); \
        *(uint2*)(dr_ + c_ * 256 + l * 4) = o_;                           \
      } } }

#define LA(dst, z_, s_) {                                                 \
    const int kc_ = (z_) * 4 + ((s_) >> 2), ks_ = (s_) & 3;               \
    const char* b_ = XbT2 +                                               \
        ((((size_t)kc_ * 16 + 2 * wv) * 4 + ks_) << 10) + l * 16;         \
    dst[0] = *(const bf16x8*)b_;                                          \
    dst[1] = *(const bf16x8*)(b_ + 4096); }

#define STEP(Ar, s_) {                                                    \
    bf16x8 bf_[4];                                                        \
    _Pragma("unroll")                                                     \
    for (int j_ = 0; j_ < 4; ++j_)                                        \
      bf_[j_] = *(const bf16x8*)&Bp[(j_ * 16 + lm) * PROW + (s_) * 32 + hq * 8]; \
    _Pragma("unroll")                                                     \
    for (int i_ = 0; i_ < 2; ++i_)                                        \
      _Pragma("unroll")                                                   \
      for (int j_ = 0; j_ < 4; ++j_)                                      \
        acc[i_][j_] = __builtin_amdgcn_mfma_f32_16x16x32_bf16(Ar[i_], bf_[j_], acc[i_][j_], 0, 0, 0); }

#pragma unroll 1
  for (int z = 0; z < 16; ++z) {
    if (z) __syncthreads();   // all waves done reading Bp before re-stage

    LOADH(z, 0)               // 8 f32x4 in flight before use
    WRITEH(0)
    LOADH(z, 1)
    WRITEH(1)
    __syncthreads();

    // phase 2: A-ring depth 2, no barriers; VM queue = A-loads only
    LA(A0, z, 0) LA(A1, z, 1)
#pragma unroll 1
    for (int su = 0; su < 14; su += 2) {
      STEP(A0, su + 0)
      LA(A0, z, su + 2)
      STEP(A1, su + 1)
      LA(A1, z, su + 3)
    }
    STEP(A0, 14)
    STEP(A1, 15)
  }
#undef LOADH
#undef WRITEH
#undef LA
#undef STEP

  // epilogue: Out[m][col] = acc + bias (bf16); col >= DIN -> 0
#pragma unroll
  for (int i = 0; i < 2; ++i) {
    const int r0 = (2 * wv + i) * 16 + hq * 4;
#pragma unroll
    for (int j = 0; j < 4; ++j) {
      const int col = n0 + j * 16 + lm;
      const float bb = (col < DIN) ? bias[col] : 0.f;
#pragma unroll
      for (int q = 0; q < 4; ++q) {
        const float v = acc[i][j][q] + bb;
        Out[(size_t)(r0 + q) * KP + col] = (col < DIN) ? (unsigned short)f2b(v) : 0;
      }
    }
  }
}

// ---------------------------------------------------------------------------
// logits partials (verified): LP[z][m][n] over 512-k chunks, grid (4,1,16)
// ---------------------------------------------------------------------------
__global__ __launch_bounds__(512)
void gemm_logits(const unsigned short* __restrict__ Qbf,
                 const unsigned short* __restrict__ Kbf, float* __restrict__ LP)
{
  const int qr = blockIdx.x & 1, qc = blockIdx.x >> 1, z = blockIdx.z;
  const int tid = threadIdx.x, lane = tid & 63, wv = tid >> 6;
  const int lm = lane & 15, lq = (lane >> 4) * 8;
  const int rowBase = qr * 128 + (wv & 3) * 32;
  const int colBase = qc * 128 + (wv >> 2) * 64;
  const int k0 = z * 512;
  f32x4 acc[2][4] = {};
#pragma unroll 4
  for (int ks = 0; ks < 16; ++ks) {
    bf16x8 a[2], b[4];
#pragma unroll
    for (int i = 0; i < 2; ++i)
      a[i] = *(const bf16x8*)(Qbf + (size_t)(rowBase + i * 16 + lm) * KP + k0 + ks * 32 + lq);
#pragma unroll
    for (int j = 0; j < 4; ++j)
      b[j] = *(const bf16x8*)(Kbf + (size_t)(colBase + j * 16 + lm) * KP + k0 + ks * 32 + lq);
#pragma unroll
    for (int i = 0; i < 2; ++i)
#pragma unroll
      for (int j = 0; j < 4; ++j)
        acc[i][j] = __builtin_amdgcn_mfma_f32_16x16x32_bf16(a[i], b[j], acc[i][j], 0, 0, 0);
  }
  float* out = LP + (size_t)z * 65536;
#pragma unroll
  for (int i = 0; i < 2; ++i) {
    const int r0 = rowBase + i * 16 + (lane >> 4) * 4;
#pragma unroll
    for (int j = 0; j < 4; ++j) {
      const int col = colBase + j * 16 + lm;
#pragma unroll
      for (int q = 0; q < 4; ++q)
        out[(size_t)(r0 + q) * 256 + col] = acc[i][j][q];
    }
  }
}

// ---------------------------------------------------------------------------
// fused: sum 16 logit partials -> row softmax -> atomicAdd into abar (w/ 1/256)
// ---------------------------------------------------------------------------
__global__ void softmax_fused(const float* __restrict__ LP, float* __restrict__ abar)
{
  __shared__ float red[8];
  const int m = blockIdx.x, t = threadIdx.x;
  float v = 0.f;
#pragma unroll
  for (int zz = 0; zz < 16; ++zz) v += LP[(size_t)zz * 65536 + m * 256 + t];
  const float scale = 1.0f / sqrtf((float)DIN);
  float mx = v;
#pragma unroll
  for (int o = 32; o >= 1; o >>= 1) mx = fmaxf(mx, __shfl_xor(mx, o, 64));
  if ((t & 63) == 0) red[t >> 6] = mx;
  __syncthreads();
  mx = fmaxf(fmaxf(red[0], red[1]), fmaxf(red[2], red[3]));
  float e = __expf((v - mx) * scale);
  float s = e;
#pragma unroll
  for (int o = 32; o >= 1; o >>= 1) s += __shfl_xor(s, o, 64);
  if ((t & 63) == 0) red[4 + (t >> 6)] = s;
  __syncthreads();
  s = red[4] + red[5] + red[6] + red[7];
  atomicAdd(&abar[t], e * (1.0f / 256.0f) / s);
}

// y[c] = sum_m abar[m] * X[m][c]
__global__ void y_kernel(const float* __restrict__ X, const float* __restrict__ abar,
                         float* __restrict__ y)
{
  __shared__ float ab[256];
  ab[threadIdx.x] = abar[threadIdx.x];
  __syncthreads();
  const int c = blockIdx.x * 256 + threadIdx.x;
  if (c >= DIN) return;
  float s = 0.f;
#pragma unroll 8
  for (int m = 0; m < 256; ++m) s += ab[m] * X[(size_t)m * DIN + c];
  y[c] = s;
}

// ctx[d] = Wv[d,:]·y + bv[d] — one row per wave; 30 branchless f32x4 iters
__global__ __launch_bounds__(512)
void ctx_mv(const float* __restrict__ Wv, const float* __restrict__ y,
            const float* __restrict__ bv, float* __restrict__ ctx)
{
  const int wv = threadIdx.x >> 6, l = threadIdx.x & 63;
  const int row = blockIdx.x * 8 + wv;
  if (row >= DIN) return;
  const float* wr_ = Wv + (size_t)row * DIN;
  float s = 0.f;
#pragma unroll 5
  for (int it = 0; it < 30; ++it) {
    const int k = it * 256 + l * 4;
    f32x4 w4 = __builtin_nontemporal_load((const f32x4*)(wr_ + k));
    float4 y4 = *(const float4*)(y + k);
    s = fmaf(w4[0], y4.x, s);
    s = fmaf(w4[1], y4.y, s);
    s = fmaf(w4[2], y4.z, s);
    s = fmaf(w4[3], y4.w, s);
  }
  if (l < 6) s += wr_[7680 + l] * y[7680 + l];
#pragma unroll
  for (int o = 32; o >= 1; o >>= 1) s += __shfl_xor(s, o, 64);
  if (l == 0) ctx[row] = s + bv[row];
}

// base[j] += sum_{i in chunk} ctx[i] * (mu+sg*ep)[i][DIN+j]
__global__ void base_kernel(const float* __restrict__ mu, const float* __restrict__ sg,
                            const float* __restrict__ ep, const float* __restrict__ ctx,
                            float* __restrict__ base)
{
  const int j = threadIdx.x;
  if (j >= HOUT) return;
  const int i0 = blockIdx.x * 31;
  const int i1 = min(i0 + 31, DIN);
  float acc = 0.f;
#pragma unroll 4
  for (int i = i0; i < i1; ++i) {
    const size_t idx = (size_t)i * NNODE + DIN + j;
    acc = fmaf(ctx[i], fmaf(sg[idx], ep[idx], mu[idx]), acc);
  }
  atomicAdd(&base[j], acc);
}

// WsG[t][j] = (mu+sg*ep)[DIN+t][DIN+j]
__global__ void ws_kernel(const float* __restrict__ mu, const float* __restrict__ sg,
                          const float* __restrict__ ep, float* __restrict__ WsG)
{
  const int t = blockIdx.x;
  const int j = threadIdx.x;
  if (j >= HOUT) return;
  const size_t idx = (size_t)(DIN + t) * NNODE + DIN + j;
  WsG[t * HOUT + j] = fmaf(sg[idx], ep[idx], mu[idx]);
}

// ---------------------------------------------------------------------------
// scan2 (verified R6): latency-minimal sequential NEAT scan. 1 wave.
// ---------------------------------------------------------------------------
__global__ __launch_bounds__(64, 1)
void scan2(const float* __restrict__ WsG, const float* __restrict__ base,
           const float* __restrict__ bmu, const float* __restrict__ bsg,
           const float* __restrict__ epb, float* __restrict__ out)
{
  __shared__ __align__(16) float tile[32 * HOUT + 128];
  const int l = threadIdx.x;

  float a0, a1, a2, a3, a4;
  {
    int j = l;       a0 = base[j] + bmu[j] + bsg[j] * epb[j];
    j = l + 64;      a1 = base[j] + bmu[j] + bsg[j] * epb[j];
    j = l + 128;     a2 = base[j] + bmu[j] + bsg[j] * epb[j];
    j = l + 192;     a3 = base[j] + bmu[j] + bsg[j] * epb[j];
    j = l + 256;     a4 = (j < HOUT) ? (base[j] + bmu[j] + bsg[j] * epb[j]) : 0.f;
  }

  float4 stg[33];
  auto LOADT = [&](int tb) {
    const int nfl = ((tb == 8) ? 4 : 32) * HOUT;
    const float* src = WsG + tb * 32 * HOUT;
#pragma unroll
    for (int c = 0; c < 33; ++c) {
      const int o = c * 256 + l * 4;
      if (o < nfl) stg[c] = *(const float4*)(src + o);
    }
  };
  auto WRITET = [&](int tb) {
    const int nfl = ((tb == 8) ? 4 : 32) * HOUT;
#pragma unroll
    for (int c = 0; c < 33; ++c) {
      const int o = c * 256 + l * 4;
      if (o < nfl) *(float4*)&tile[o] = stg[c];
    }
  };

  float w0, w1, w2, w3, w4;
  auto PRER = [&](int trow) {
    const float* tr = tile + trow * HOUT;
    w0 = tr[l]; w1 = tr[l + 64]; w2 = tr[l + 128]; w3 = tr[l + 192]; w4 = tr[l + 256];
  };

  auto inner = [&](auto Bc, int tb, int nrows) {
    constexpr int B = Bc.value;
    for (int tt = 0; tt < nrows; ++tt) {
      const int t = tb * 32 + tt;
      float pre;
      if constexpr (B == 0) pre = readlane_f(a0, t & 63);
      else if constexpr (B == 1) pre = readlane_f(a1, t & 63);
      else if constexpr (B == 2) pre = readlane_f(a2, t & 63);
      else if constexpr (B == 3) pre = readlane_f(a3, t & 63);
      else pre = readlane_f(a4, t & 63);
      const float pc = fminf(fmaxf(pre, -12.f), 12.f);
      const float e = __expf(2.f * pc);
      const float vt = 1.f - 2.f / (e + 1.f);
      if (t >= 256 && l == 0) out[t - 256] = vt;
      if (l > t)            a0 = fmaf(vt, w0, a0);
      if (l + 64 > t)       a1 = fmaf(vt, w1, a1);
      if (l + 128 > t)      a2 = fmaf(vt, w2, a2);
      if (l + 192 > t)      a3 = fmaf(vt, w3, a3);
      if (l + 256 > t && l + 256 < HOUT) a4 = fmaf(vt, w4, a4);
      if (tt + 1 < nrows) PRER(tt + 1);
    }
  };

  LOADT(0); WRITET(0); PRER(0);

#define TILE_STEP(tb, B, nr)                                    \
  { if ((tb) < 8) LOADT((tb) + 1);                              \
    inner(std::integral_constant<int, B>{}, (tb), (nr));        \
    if ((tb) < 8) { WRITET((tb) + 1); PRER(0); } }

  TILE_STEP(0, 0, 32)
  TILE_STEP(1, 0, 32)
  TILE_STEP(2, 1, 32)
  TILE_STEP(3, 1, 32)
  TILE_STEP(4, 2, 32)
  TILE_STEP(5, 2, 32)
  TILE_STEP(6, 3, 32)
  TILE_STEP(7, 3, 32)
  TILE_STEP(8, 4, 4)
#undef TILE_STEP
}

// ---------------------------------------------------------------------------
extern "C" void kernel_launch(void* const* d_in, const int* in_sizes, int n_in,
                              void* d_out, int out_size, void* d_ws, size_t ws_size,
                              hipStream_t stream)
{
  const float* X   = (const float*)d_in[0];
  const float* Wq  = (const float*)d_in[1];
  const float* bq  = (const float*)d_in[2];
  const float* Wk  = (const float*)d_in[3];
  const float* bk  = (const float*)d_in[4];
  const float* Wv  = (const float*)d_in[5];
  const float* bv  = (const float*)d_in[6];
  const float* wmu = (const float*)d_in[7];
  const float* wsg = (const float*)d_in[8];
  const float* bmu = (const float*)d_in[9];
  const float* bsg = (const float*)d_in[10];
  const float* epw = (const float*)d_in[11];
  const float* epb = (const float*)d_in[12];

  char* p = (char*)d_ws;
  auto alloc = [&](size_t bytes) -> char* {
    char* r = p;
    p += (bytes + 255) & ~(size_t)255;
    return r;
  };
  char* XbT2 = alloc((size_t)64 * 65536);                                  // 4MB
  unsigned short* Qbf = (unsigned short*)alloc((size_t)256 * KP * 2);      // 4MB
  unsigned short* Kbf = (unsigned short*)alloc((size_t)256 * KP * 2);      // 4MB
  float* LP   = (float*)alloc((size_t)16 * 65536 * 4);                     // 4MB
  float* abar = (float*)alloc(256 * 4);
  float* y    = (float*)alloc(7686 * 4);
  float* ctx  = (float*)alloc(7686 * 4);
  float* base = (float*)alloc(HOUT * 4);
  float* WsG  = (float*)alloc((size_t)HOUT * HOUT * 4 + 1024);

  prep_x2<<<dim3(256), dim3(256), 0, stream>>>(X, XbT2);
  ws_kernel<<<dim3(260), dim3(320), 0, stream>>>(wmu, wsg, epw, WsG);  // off critical tail
  (void)hipMemsetAsync(abar, 0, 256 * 4, stream);
  (void)hipMemsetAsync(base, 0, HOUT * 4, stream);
  (void)hipMemsetAsync(Qbf, 0, (size_t)256 * KP * 2, stream);
  (void)hipMemsetAsync(Kbf, 0, (size_t)256 * KP * 2, stream);

  gemm_qk10<<<dim3(121, 2), dim3(512), 0, stream>>>(XbT2, Wq, Wk, bq, bk, Qbf, Kbf);
  gemm_logits<<<dim3(4, 1, 16), dim3(512), 0, stream>>>(Qbf, Kbf, LP);
  softmax_fused<<<dim3(256), dim3(256), 0, stream>>>(LP, abar);
  y_kernel<<<dim3(31), dim3(256), 0, stream>>>(X, abar, y);
  ctx_mv<<<dim3(961), dim3(512), 0, stream>>>(Wv, y, bv, ctx);
  base_kernel<<<dim3(256), dim3(320), 0, stream>>>(wmu, wsg, epw, ctx, base);
  scan2<<<dim3(1), dim3(64), 0, stream>>>(WsG, base, bmu, bsg, epb, (float*)d_out);
}